// Round 1
// baseline (711.703 us; speedup 1.0000x reference)
//
#include <hip/hip_runtime.h>

typedef __bf16 bf16;
typedef __attribute__((ext_vector_type(8))) __bf16 bf16x8;
typedef __attribute__((ext_vector_type(4))) float f32x4;

#define MFMA16(a, b, c) __builtin_amdgcn_mfma_f32_16x16x32_bf16((a), (b), (c), 0, 0, 0)

// Shapes (fixed by the problem)
// B=4, L=2048, DIM=1024, H=16, HD=64. M = B*L = 8192.

static __device__ __forceinline__ bf16x8 cvt_f4x2(const float4 a, const float4 b) {
  bf16x8 r;
  r[0] = (bf16)a.x; r[1] = (bf16)a.y; r[2] = (bf16)a.z; r[3] = (bf16)a.w;
  r[4] = (bf16)b.x; r[5] = (bf16)b.y; r[6] = (bf16)b.z; r[7] = (bf16)b.w;
  return r;
}

// ---------------------------------------------------------------------------
// GEMM1: qkv = x @ w_qkv + b_qkv, scattered to Q/K/V buffers [B*H][L][64] bf16
// 128x128 tile, BK=32, 4 waves, per-wave 64x64 (4x4 MFMA frags). Ref: m90/m97
// verified layouts: A-frag row=lane&15 k=8*(lane>>4)+e; B-frag (from B^T in
// LDS) col=lane&15 k=8*(lane>>4)+e; C row=(lane>>4)*4+i col=lane&15.
// ---------------------------------------------------------------------------
__global__ __launch_bounds__(256) void gemm_qkv_kernel(
    const float* __restrict__ X, const float* __restrict__ W,
    const float* __restrict__ bias, bf16* __restrict__ Qb,
    bf16* __restrict__ Kb, bf16* __restrict__ Vb) {
  constexpr int K = 1024, N = 3072;
  __shared__ __align__(16) bf16 sA[128][40];  // pad 32->40: 2-way max on frag reads
  __shared__ __align__(16) bf16 sB[128][40];  // B^T tile: [n][k]
  const int tid = threadIdx.x;
  const int m0 = blockIdx.y * 128;
  const int n0 = blockIdx.x * 128;
  const int wid = tid >> 6, lane = tid & 63;
  const int wr = wid >> 1, wc = wid & 1;
  const int lg = lane >> 4, lr = lane & 15;

  const f32x4 fzero = {0.f, 0.f, 0.f, 0.f};
  f32x4 acc[4][4];
#pragma unroll
  for (int m = 0; m < 4; ++m)
#pragma unroll
    for (int n = 0; n < 4; ++n) acc[m][n] = fzero;

  const int ar = tid >> 1, ak = (tid & 1) * 16;   // A: 128 rows x 32 k, 16 f32/thread
  const int bk = tid >> 3, bn = (tid & 7) * 16;   // B: 32 k-rows x 128 n, 16 f32/thread
  const float* aptr = X + (size_t)(m0 + ar) * K + ak;
  const float* bptr = W + (size_t)bk * N + n0 + bn;

  for (int k0 = 0; k0 < K; k0 += 32) {
    const float4* a4 = (const float4*)aptr;
    float4 fa0 = a4[0], fa1 = a4[1], fa2 = a4[2], fa3 = a4[3];
    const float4* b4 = (const float4*)bptr;
    float4 g0 = b4[0], g1 = b4[1], g2 = b4[2], g3 = b4[3];

    *(bf16x8*)&sA[ar][ak]     = cvt_f4x2(fa0, fa1);
    *(bf16x8*)&sA[ar][ak + 8] = cvt_f4x2(fa2, fa3);

    // transpose-store B tile as [n][k]
    sB[bn +  0][bk] = (bf16)g0.x;  sB[bn +  1][bk] = (bf16)g0.y;
    sB[bn +  2][bk] = (bf16)g0.z;  sB[bn +  3][bk] = (bf16)g0.w;
    sB[bn +  4][bk] = (bf16)g1.x;  sB[bn +  5][bk] = (bf16)g1.y;
    sB[bn +  6][bk] = (bf16)g1.z;  sB[bn +  7][bk] = (bf16)g1.w;
    sB[bn +  8][bk] = (bf16)g2.x;  sB[bn +  9][bk] = (bf16)g2.y;
    sB[bn + 10][bk] = (bf16)g2.z;  sB[bn + 11][bk] = (bf16)g2.w;
    sB[bn + 12][bk] = (bf16)g3.x;  sB[bn + 13][bk] = (bf16)g3.y;
    sB[bn + 14][bk] = (bf16)g3.z;  sB[bn + 15][bk] = (bf16)g3.w;
    __syncthreads();

    bf16x8 af[4], bfv[4];
#pragma unroll
    for (int m = 0; m < 4; ++m)
      af[m] = *(const bf16x8*)&sA[wr * 64 + m * 16 + lr][8 * lg];
#pragma unroll
    for (int n = 0; n < 4; ++n)
      bfv[n] = *(const bf16x8*)&sB[wc * 64 + n * 16 + lr][8 * lg];
#pragma unroll
    for (int m = 0; m < 4; ++m)
#pragma unroll
      for (int n = 0; n < 4; ++n)
        acc[m][n] = MFMA16(af[m], bfv[n], acc[m][n]);
    __syncthreads();

    aptr += 32;
    bptr += (size_t)32 * N;
  }

  // n0 is a multiple of 128, so the whole block writes one of Q/K/V.
  bf16* dst = (n0 < 1024) ? Qb : ((n0 < 2048) ? Kb : Vb);
#pragma unroll
  for (int m = 0; m < 4; ++m) {
#pragma unroll
    for (int n = 0; n < 4; ++n) {
      const int colg = n0 + wc * 64 + n * 16 + lr;   // 0..3071
      const int col = colg & 1023;
      const int h = col >> 6, d = col & 63;
      const float bv = bias[colg];
#pragma unroll
      for (int i = 0; i < 4; ++i) {
        const int row = m0 + wr * 64 + m * 16 + lg * 4 + i;  // 0..8191
        const int bb = row >> 11, ll = row & 2047;
        dst[((size_t)((bb * 16 + h) * 2048 + ll)) * 64 + d] =
            (bf16)(acc[m][n][i] + bv);
      }
    }
  }
}

// ---------------------------------------------------------------------------
// Causal flash attention. Grid (L/64, B*H), 256 threads = 4 waves.
// Each wave owns 16 q-rows; KV tiles of 32 shared in LDS across waves.
// V staged TRANSPOSED ([d][kv]) so the PV B-fragment is a contiguous b128.
// P goes through per-wave LDS to re-layout C-frag -> A-frag (in-wave, no bar).
// ---------------------------------------------------------------------------
__global__ __launch_bounds__(256) void attn_kernel(
    const bf16* __restrict__ Qb, const bf16* __restrict__ Kb,
    const bf16* __restrict__ Vb, bf16* __restrict__ O) {
  __shared__ __align__(16) bf16 sK[32][72];      // [kv][d], pad 64->72
  __shared__ __align__(16) bf16 sVT[64][48];     // [d][kv], pad 32->48
  __shared__ __align__(16) bf16 sP[4][16][40];   // per-wave [q][kv], pad 32->40
  const int tid = threadIdx.x;
  const int qt = blockIdx.x, bh = blockIdx.y;
  const int q0 = qt * 64;
  const int wid = tid >> 6, lane = tid & 63;
  const int lg = lane >> 4, lr = lane & 15;
  const size_t base = (size_t)bh * (2048 * 64);

  // Q fragments hoisted (d-chunks 0,1)
  const int qrow = q0 + wid * 16 + lr;
  const bf16x8 qf0 = *(const bf16x8*)&Qb[base + (size_t)qrow * 64 + 8 * lg];
  const bf16x8 qf1 = *(const bf16x8*)&Qb[base + (size_t)qrow * 64 + 32 + 8 * lg];

  const f32x4 fzero = {0.f, 0.f, 0.f, 0.f};
  f32x4 o[4];
  float m_[4], ssum[4];
#pragma unroll
  for (int n = 0; n < 4; ++n) o[n] = fzero;
#pragma unroll
  for (int i = 0; i < 4; ++i) { m_[i] = -1e30f; ssum[i] = 0.f; }

  const int sr = tid >> 3, sd = (tid & 7) * 8;   // staging: 32 rows x 64 d
  const int ntiles = 2 * qt + 2;                 // kv up to q0+64

  for (int t = 0; t < ntiles; ++t) {
    const int kv0 = t * 32;
    __syncthreads();  // previous-iter LDS reads complete
    *(bf16x8*)&sK[sr][sd] =
        *(const bf16x8*)&Kb[base + (size_t)(kv0 + sr) * 64 + sd];
    const bf16x8 vv = *(const bf16x8*)&Vb[base + (size_t)(kv0 + sr) * 64 + sd];
#pragma unroll
    for (int j = 0; j < 8; ++j) sVT[sd + j][sr] = vv[j];
    __syncthreads();

    // S = Q K^T  (two 16-kv sub-tiles)
    f32x4 s[2];
#pragma unroll
    for (int sub = 0; sub < 2; ++sub) {
      f32x4 sc = fzero;
      const bf16x8 kf0 = *(const bf16x8*)&sK[sub * 16 + lr][8 * lg];
      const bf16x8 kf1 = *(const bf16x8*)&sK[sub * 16 + lr][32 + 8 * lg];
      sc = MFMA16(qf0, kf0, sc);
      sc = MFMA16(qf1, kf1, sc);
      s[sub] = sc;
    }

    // scale + causal mask + online softmax (rows live in 16-lane groups)
#pragma unroll
    for (int i = 0; i < 4; ++i) {
      const int qi = q0 + wid * 16 + lg * 4 + i;
      float s0 = s[0][i] * 0.125f;
      float s1 = s[1][i] * 0.125f;
      s0 = (kv0 + lr > qi) ? -1e30f : s0;
      s1 = (kv0 + 16 + lr > qi) ? -1e30f : s1;
      float rm = fmaxf(s0, s1);
      rm = fmaxf(rm, __shfl_xor(rm, 1));
      rm = fmaxf(rm, __shfl_xor(rm, 2));
      rm = fmaxf(rm, __shfl_xor(rm, 4));
      rm = fmaxf(rm, __shfl_xor(rm, 8));
      const float mn = fmaxf(m_[i], rm);
      const float corr = __expf(m_[i] - mn);  // ==0 when first real tile lands
      const float p0 = __expf(s0 - mn);
      const float p1 = __expf(s1 - mn);
      float rs = p0 + p1;
      rs += __shfl_xor(rs, 1);
      rs += __shfl_xor(rs, 2);
      rs += __shfl_xor(rs, 4);
      rs += __shfl_xor(rs, 8);
      ssum[i] = ssum[i] * corr + rs;
      m_[i] = mn;
#pragma unroll
      for (int n = 0; n < 4; ++n) o[n][i] = o[n][i] * corr;
      sP[wid][lg * 4 + i][lr] = (bf16)p0;
      sP[wid][lg * 4 + i][16 + lr] = (bf16)p1;
    }

    // O += P V  (A-frag of P from per-wave LDS; in-wave LDS ops are ordered)
    const bf16x8 pf = *(const bf16x8*)&sP[wid][lr][8 * lg];
#pragma unroll
    for (int n = 0; n < 4; ++n) {
      const bf16x8 vf = *(const bf16x8*)&sVT[n * 16 + lr][8 * lg];
      o[n] = MFMA16(pf, vf, o[n]);
    }
  }

  const int b = bh >> 4, h = bh & 15;
#pragma unroll
  for (int n = 0; n < 4; ++n) {
#pragma unroll
    for (int i = 0; i < 4; ++i) {
      const int qi = q0 + wid * 16 + lg * 4 + i;
      const int d = n * 16 + lr;
      O[((size_t)(b * 2048 + qi)) * 1024 + h * 64 + d] =
          (bf16)(o[n][i] / ssum[i]);
    }
  }
}

// ---------------------------------------------------------------------------
// GEMM2: out = attn @ w_out + b_out  (A is bf16, output f32)
// ---------------------------------------------------------------------------
__global__ __launch_bounds__(256) void gemm_out_kernel(
    const bf16* __restrict__ A, const float* __restrict__ W,
    const float* __restrict__ bias, float* __restrict__ Out) {
  constexpr int K = 1024, N = 1024;
  __shared__ __align__(16) bf16 sA[128][40];
  __shared__ __align__(16) bf16 sB[128][40];
  const int tid = threadIdx.x;
  const int m0 = blockIdx.y * 128;
  const int n0 = blockIdx.x * 128;
  const int wid = tid >> 6, lane = tid & 63;
  const int wr = wid >> 1, wc = wid & 1;
  const int lg = lane >> 4, lr = lane & 15;

  const f32x4 fzero = {0.f, 0.f, 0.f, 0.f};
  f32x4 acc[4][4];
#pragma unroll
  for (int m = 0; m < 4; ++m)
#pragma unroll
    for (int n = 0; n < 4; ++n) acc[m][n] = fzero;

  const int ar = tid >> 1, ak = (tid & 1) * 16;
  const int bk = tid >> 3, bn = (tid & 7) * 16;
  const bf16* aptr = A + (size_t)(m0 + ar) * K + ak;
  const float* bptr = W + (size_t)bk * N + n0 + bn;

  for (int k0 = 0; k0 < K; k0 += 32) {
    const bf16x8 lo = ((const bf16x8*)aptr)[0];
    const bf16x8 hi = ((const bf16x8*)aptr)[1];
    const float4* b4 = (const float4*)bptr;
    float4 g0 = b4[0], g1 = b4[1], g2 = b4[2], g3 = b4[3];

    *(bf16x8*)&sA[ar][ak]     = lo;
    *(bf16x8*)&sA[ar][ak + 8] = hi;

    sB[bn +  0][bk] = (bf16)g0.x;  sB[bn +  1][bk] = (bf16)g0.y;
    sB[bn +  2][bk] = (bf16)g0.z;  sB[bn +  3][bk] = (bf16)g0.w;
    sB[bn +  4][bk] = (bf16)g1.x;  sB[bn +  5][bk] = (bf16)g1.y;
    sB[bn +  6][bk] = (bf16)g1.z;  sB[bn +  7][bk] = (bf16)g1.w;
    sB[bn +  8][bk] = (bf16)g2.x;  sB[bn +  9][bk] = (bf16)g2.y;
    sB[bn + 10][bk] = (bf16)g2.z;  sB[bn + 11][bk] = (bf16)g2.w;
    sB[bn + 12][bk] = (bf16)g3.x;  sB[bn + 13][bk] = (bf16)g3.y;
    sB[bn + 14][bk] = (bf16)g3.z;  sB[bn + 15][bk] = (bf16)g3.w;
    __syncthreads();

    bf16x8 af[4], bfv[4];
#pragma unroll
    for (int m = 0; m < 4; ++m)
      af[m] = *(const bf16x8*)&sA[wr * 64 + m * 16 + lr][8 * lg];
#pragma unroll
    for (int n = 0; n < 4; ++n)
      bfv[n] = *(const bf16x8*)&sB[wc * 64 + n * 16 + lr][8 * lg];
#pragma unroll
    for (int m = 0; m < 4; ++m)
#pragma unroll
      for (int n = 0; n < 4; ++n)
        acc[m][n] = MFMA16(af[m], bfv[n], acc[m][n]);
    __syncthreads();

    aptr += 32;
    bptr += (size_t)32 * N;
  }

#pragma unroll
  for (int m = 0; m < 4; ++m) {
#pragma unroll
    for (int n = 0; n < 4; ++n) {
      const int colg = n0 + wc * 64 + n * 16 + lr;
      const float bv = bias[colg];
#pragma unroll
      for (int i = 0; i < 4; ++i) {
        const int row = m0 + wr * 64 + m * 16 + lg * 4 + i;
        Out[(size_t)row * N + colg] = acc[m][n][i] + bv;
      }
    }
  }
}

extern "C" void kernel_launch(void* const* d_in, const int* in_sizes, int n_in,
                              void* d_out, int out_size, void* d_ws,
                              size_t ws_size, hipStream_t stream) {
  const float* x     = (const float*)d_in[0];
  const float* w_qkv = (const float*)d_in[1];
  const float* b_qkv = (const float*)d_in[2];
  const float* w_out = (const float*)d_in[3];
  const float* b_out = (const float*)d_in[4];
  float* out = (float*)d_out;

  char* ws = (char*)d_ws;
  const size_t SZ = (size_t)8192 * 1024 * sizeof(bf16);  // 16 MB each
  bf16* Qb = (bf16*)(ws);           // [B*H][L][64]
  bf16* Kb = (bf16*)(ws + SZ);
  bf16* Vb = (bf16*)(ws + 2 * SZ);
  bf16* Ab = (bf16*)(ws + 3 * SZ);  // attn out, [B*L][1024]

  gemm_qkv_kernel<<<dim3(24, 64), 256, 0, stream>>>(x, w_qkv, b_qkv, Qb, Kb, Vb);
  attn_kernel<<<dim3(32, 64), 256, 0, stream>>>(Qb, Kb, Vb, Ab);
  gemm_out_kernel<<<dim3(8, 64), 256, 0, stream>>>(Ab, w_out, b_out, out);
}

// Round 2
// 561.439 us; speedup vs baseline: 1.2676x; 1.2676x over previous
//
#include <hip/hip_runtime.h>

typedef __bf16 bf16;
typedef __attribute__((ext_vector_type(8))) __bf16 bf16x8;
typedef __attribute__((ext_vector_type(4))) __bf16 bf16x4;
typedef __attribute__((ext_vector_type(4))) float f32x4;

#define MFMA16(a, b, c) __builtin_amdgcn_mfma_f32_16x16x32_bf16((a), (b), (c), 0, 0, 0)

// Shapes: B=4, L=2048, DIM=1024, H=16, HD=64. M = B*L = 8192.

static __device__ __forceinline__ bf16x8 cvt_f4x2(const float4 a, const float4 b) {
  bf16x8 r;
  r[0] = (bf16)a.x; r[1] = (bf16)a.y; r[2] = (bf16)a.z; r[3] = (bf16)a.w;
  r[4] = (bf16)b.x; r[5] = (bf16)b.y; r[6] = (bf16)b.z; r[7] = (bf16)b.w;
  return r;
}

// ---------------------------------------------------------------------------
// GEMM1: qkv = x @ w_qkv + b_qkv. Q,K scattered to [B*H][L][64]; V scattered
// TRANSPOSED to Vt[B*H][64][L] (i-index of C-frag runs along tokens ->
// contiguous bf16x4 store, and attention's PV B-frag becomes a natural b128).
// ---------------------------------------------------------------------------
__global__ __launch_bounds__(256) void gemm_qkv_kernel(
    const float* __restrict__ X, const float* __restrict__ W,
    const float* __restrict__ bias, bf16* __restrict__ Qb,
    bf16* __restrict__ Kb, bf16* __restrict__ Vt) {
  constexpr int K = 1024, N = 3072;
  __shared__ __align__(16) bf16 sA[128][40];
  __shared__ __align__(16) bf16 sB[128][40];  // B^T tile: [n][k]
  const int tid = threadIdx.x;
  const int m0 = blockIdx.y * 128;
  const int n0 = blockIdx.x * 128;
  const int wid = tid >> 6, lane = tid & 63;
  const int wr = wid >> 1, wc = wid & 1;
  const int lg = lane >> 4, lr = lane & 15;

  const f32x4 fzero = {0.f, 0.f, 0.f, 0.f};
  f32x4 acc[4][4];
#pragma unroll
  for (int m = 0; m < 4; ++m)
#pragma unroll
    for (int n = 0; n < 4; ++n) acc[m][n] = fzero;

  const int ar = tid >> 1, ak = (tid & 1) * 16;
  const int bk = tid >> 3, bn = (tid & 7) * 16;
  const float* aptr = X + (size_t)(m0 + ar) * K + ak;
  const float* bptr = W + (size_t)bk * N + n0 + bn;

  for (int k0 = 0; k0 < K; k0 += 32) {
    const float4* a4 = (const float4*)aptr;
    float4 fa0 = a4[0], fa1 = a4[1], fa2 = a4[2], fa3 = a4[3];
    const float4* b4 = (const float4*)bptr;
    float4 g0 = b4[0], g1 = b4[1], g2 = b4[2], g3 = b4[3];

    *(bf16x8*)&sA[ar][ak]     = cvt_f4x2(fa0, fa1);
    *(bf16x8*)&sA[ar][ak + 8] = cvt_f4x2(fa2, fa3);

    sB[bn +  0][bk] = (bf16)g0.x;  sB[bn +  1][bk] = (bf16)g0.y;
    sB[bn +  2][bk] = (bf16)g0.z;  sB[bn +  3][bk] = (bf16)g0.w;
    sB[bn +  4][bk] = (bf16)g1.x;  sB[bn +  5][bk] = (bf16)g1.y;
    sB[bn +  6][bk] = (bf16)g1.z;  sB[bn +  7][bk] = (bf16)g1.w;
    sB[bn +  8][bk] = (bf16)g2.x;  sB[bn +  9][bk] = (bf16)g2.y;
    sB[bn + 10][bk] = (bf16)g2.z;  sB[bn + 11][bk] = (bf16)g2.w;
    sB[bn + 12][bk] = (bf16)g3.x;  sB[bn + 13][bk] = (bf16)g3.y;
    sB[bn + 14][bk] = (bf16)g3.z;  sB[bn + 15][bk] = (bf16)g3.w;
    __syncthreads();

    bf16x8 af[4], bfv[4];
#pragma unroll
    for (int m = 0; m < 4; ++m)
      af[m] = *(const bf16x8*)&sA[wr * 64 + m * 16 + lr][8 * lg];
#pragma unroll
    for (int n = 0; n < 4; ++n)
      bfv[n] = *(const bf16x8*)&sB[wc * 64 + n * 16 + lr][8 * lg];
#pragma unroll
    for (int m = 0; m < 4; ++m)
#pragma unroll
      for (int n = 0; n < 4; ++n)
        acc[m][n] = MFMA16(af[m], bfv[n], acc[m][n]);
    __syncthreads();

    aptr += 32;
    bptr += (size_t)32 * N;
  }

  if (n0 < 2048) {
    // Q or K: natural [bh][token][d] layout, scalar stores
    bf16* dst = (n0 < 1024) ? Qb : Kb;
#pragma unroll
    for (int m = 0; m < 4; ++m) {
#pragma unroll
      for (int n = 0; n < 4; ++n) {
        const int colg = n0 + wc * 64 + n * 16 + lr;
        const int col = colg & 1023;
        const int h = col >> 6, d = col & 63;
        const float bv = bias[colg];
#pragma unroll
        for (int i = 0; i < 4; ++i) {
          const int row = m0 + wr * 64 + m * 16 + lg * 4 + i;
          const int bb = row >> 11, ll = row & 2047;
          dst[((size_t)((bb * 16 + h) * 2048 + ll)) * 64 + d] =
              (bf16)(acc[m][n][i] + bv);
        }
      }
    }
  } else {
    // V: transposed [bh][d][token]; i runs along tokens -> bf16x4 8B store
#pragma unroll
    for (int m = 0; m < 4; ++m) {
#pragma unroll
      for (int n = 0; n < 4; ++n) {
        const int colg = n0 + wc * 64 + n * 16 + lr;
        const int col = colg & 1023;
        const int h = col >> 6, d = col & 63;
        const float bv = bias[colg];
        const int row0 = m0 + wr * 64 + m * 16 + lg * 4;
        const int bb = row0 >> 11, ll0 = row0 & 2047;
        bf16x4 pk;
#pragma unroll
        for (int i = 0; i < 4; ++i) pk[i] = (bf16)(acc[m][n][i] + bv);
        *(bf16x4*)&Vt[((size_t)((bb * 16 + h) * 64 + d)) * 2048 + ll0] = pk;
      }
    }
  }
}

// ---------------------------------------------------------------------------
// Causal flash attention, swapped-QK^T (S^T = mfma(K,Q)) so softmax is
// per-lane. No K/V LDS staging (L2/L3-resident per m169) -> zero barriers.
// Grid: 2048 1-D blocks; bh = id&63 (XCD class), qt = 31-(id>>6) heavy-first.
// Per block: 4 waves x 16 q-rows = 64 q. KVBLK = 64.
// ---------------------------------------------------------------------------
__global__ __launch_bounds__(256) void attn_kernel(
    const bf16* __restrict__ Qb, const bf16* __restrict__ Kb,
    const bf16* __restrict__ Vt, bf16* __restrict__ O) {
  __shared__ __align__(16) bf16 sP[4][16][72];  // per-wave P[q16][kv64], 144B rows
  const int tid = threadIdx.x;
  const int qt = 31 - (int)(blockIdx.x >> 6);
  const int bh = blockIdx.x & 63;
  const int q0 = qt * 64;
  const int wid = tid >> 6, lane = tid & 63;
  const int lg = lane >> 4, lr = lane & 15;
  const size_t kqbase = (size_t)bh * (2048 * 64);
  const size_t vtbase = (size_t)bh * (64 * 2048);

  // Q fragments hoisted (B-frag: col=lr -> q-row, k=8*lg+e -> d, contiguous)
  const int qrow = q0 + wid * 16 + lr;
  const bf16x8 qf0 = *(const bf16x8*)&Qb[kqbase + (size_t)qrow * 64 + 8 * lg];
  const bf16x8 qf1 = *(const bf16x8*)&Qb[kqbase + (size_t)qrow * 64 + 32 + 8 * lg];

  const f32x4 fz = {0.f, 0.f, 0.f, 0.f};
  f32x4 o[4];
#pragma unroll
  for (int n = 0; n < 4; ++n) o[n] = fz;
  float m_ = -1e30f, ssum = 0.f;  // per-lane state for q = qrow

  for (int t = 0; t <= qt; ++t) {
    const int kv0 = t * 64;
    // S^T = K Q^T: A=K (row=kv), B=Q (col=q). C: row=kv=4lg+i, col=q=lr.
    f32x4 s[4];
#pragma unroll
    for (int sub = 0; sub < 4; ++sub) {
      const bf16* kr = &Kb[kqbase + (size_t)(kv0 + sub * 16 + lr) * 64 + 8 * lg];
      const bf16x8 kf0 = *(const bf16x8*)kr;
      const bf16x8 kf1 = *(const bf16x8*)(kr + 32);
      f32x4 sc = MFMA16(kf0, qf0, fz);
      s[sub] = MFMA16(kf1, qf1, sc);
    }
    // scale + causal mask + per-lane online softmax (lane owns q=qrow, 16 kv)
    float sv[16];
    float rm = -1e30f;
#pragma unroll
    for (int sub = 0; sub < 4; ++sub)
#pragma unroll
      for (int i = 0; i < 4; ++i) {
        const int kvg = kv0 + sub * 16 + lg * 4 + i;
        float v = s[sub][i] * 0.125f;
        v = (kvg > qrow) ? -1e30f : v;
        sv[sub * 4 + i] = v;
        rm = fmaxf(rm, v);
      }
    rm = fmaxf(rm, __shfl_xor(rm, 16));
    rm = fmaxf(rm, __shfl_xor(rm, 32));
    const float mn = fmaxf(m_, rm);
    const float corr = __expf(m_ - mn);
    m_ = mn;
    float rs = 0.f;
#pragma unroll
    for (int sub = 0; sub < 4; ++sub) {
      const float p0 = __expf(sv[sub * 4 + 0] - mn);
      const float p1 = __expf(sv[sub * 4 + 1] - mn);
      const float p2 = __expf(sv[sub * 4 + 2] - mn);
      const float p3 = __expf(sv[sub * 4 + 3] - mn);
      rs += (p0 + p1) + (p2 + p3);
      bf16x4 pk;
      pk[0] = (bf16)p0; pk[1] = (bf16)p1; pk[2] = (bf16)p2; pk[3] = (bf16)p3;
      *(bf16x4*)&sP[wid][lr][16 * sub + 4 * lg] = pk;  // P[q=lr][kv 16sub+4lg..]
    }
    rs += __shfl_xor(rs, 16);
    rs += __shfl_xor(rs, 32);
    ssum = ssum * corr + rs;
    // O rows are q=4lg+i; fetch matching corr from lane 4lg+i (lr==4lg+i,lg=0)
    float cr[4];
#pragma unroll
    for (int i = 0; i < 4; ++i) cr[i] = __shfl(corr, 4 * lg + i);
#pragma unroll
    for (int n = 0; n < 4; ++n)
#pragma unroll
      for (int i = 0; i < 4; ++i) o[n][i] *= cr[i];
    // O += P V: A=P (row=q=lr, k=kv), B=V from Vt (k=kv contiguous, col=d=lr)
#pragma unroll
    for (int c2 = 0; c2 < 2; ++c2) {
      const bf16x8 pf = *(const bf16x8*)&sP[wid][lr][32 * c2 + 8 * lg];
#pragma unroll
      for (int n = 0; n < 4; ++n) {
        const bf16x8 vf = *(const bf16x8*)&Vt[vtbase + (size_t)(n * 16 + lr) * 2048 +
                                             kv0 + 32 * c2 + 8 * lg];
        o[n] = MFMA16(pf, vf, o[n]);
      }
    }
  }

  const float rinv = 1.f / ssum;  // valid for q = qrow (lane's own q)
  float rv[4];
#pragma unroll
  for (int i = 0; i < 4; ++i) rv[i] = __shfl(rinv, 4 * lg + i);
  const int b = bh >> 4, h = bh & 15;
#pragma unroll
  for (int n = 0; n < 4; ++n)
#pragma unroll
    for (int i = 0; i < 4; ++i) {
      const int q = q0 + wid * 16 + 4 * lg + i;
      O[((size_t)(b * 2048 + q)) * 1024 + h * 64 + n * 16 + lr] =
          (bf16)(o[n][i] * rv[i]);
    }
}

// ---------------------------------------------------------------------------
// GEMM2: out = attn @ w_out + b_out  (A bf16, output f32)
// ---------------------------------------------------------------------------
__global__ __launch_bounds__(256) void gemm_out_kernel(
    const bf16* __restrict__ A, const float* __restrict__ W,
    const float* __restrict__ bias, float* __restrict__ Out) {
  constexpr int K = 1024, N = 1024;
  __shared__ __align__(16) bf16 sA[128][40];
  __shared__ __align__(16) bf16 sB[128][40];
  const int tid = threadIdx.x;
  const int m0 = blockIdx.y * 128;
  const int n0 = blockIdx.x * 128;
  const int wid = tid >> 6, lane = tid & 63;
  const int wr = wid >> 1, wc = wid & 1;
  const int lg = lane >> 4, lr = lane & 15;

  const f32x4 fzero = {0.f, 0.f, 0.f, 0.f};
  f32x4 acc[4][4];
#pragma unroll
  for (int m = 0; m < 4; ++m)
#pragma unroll
    for (int n = 0; n < 4; ++n) acc[m][n] = fzero;

  const int ar = tid >> 1, ak = (tid & 1) * 16;
  const int bk = tid >> 3, bn = (tid & 7) * 16;
  const bf16* aptr = A + (size_t)(m0 + ar) * K + ak;
  const float* bptr = W + (size_t)bk * N + n0 + bn;

  for (int k0 = 0; k0 < K; k0 += 32) {
    const bf16x8 lo = ((const bf16x8*)aptr)[0];
    const bf16x8 hi = ((const bf16x8*)aptr)[1];
    const float4* b4 = (const float4*)bptr;
    float4 g0 = b4[0], g1 = b4[1], g2 = b4[2], g3 = b4[3];

    *(bf16x8*)&sA[ar][ak]     = lo;
    *(bf16x8*)&sA[ar][ak + 8] = hi;

    sB[bn +  0][bk] = (bf16)g0.x;  sB[bn +  1][bk] = (bf16)g0.y;
    sB[bn +  2][bk] = (bf16)g0.z;  sB[bn +  3][bk] = (bf16)g0.w;
    sB[bn +  4][bk] = (bf16)g1.x;  sB[bn +  5][bk] = (bf16)g1.y;
    sB[bn +  6][bk] = (bf16)g1.z;  sB[bn +  7][bk] = (bf16)g1.w;
    sB[bn +  8][bk] = (bf16)g2.x;  sB[bn +  9][bk] = (bf16)g2.y;
    sB[bn + 10][bk] = (bf16)g2.z;  sB[bn + 11][bk] = (bf16)g2.w;
    sB[bn + 12][bk] = (bf16)g3.x;  sB[bn + 13][bk] = (bf16)g3.y;
    sB[bn + 14][bk] = (bf16)g3.z;  sB[bn + 15][bk] = (bf16)g3.w;
    __syncthreads();

    bf16x8 af[4], bfv[4];
#pragma unroll
    for (int m = 0; m < 4; ++m)
      af[m] = *(const bf16x8*)&sA[wr * 64 + m * 16 + lr][8 * lg];
#pragma unroll
    for (int n = 0; n < 4; ++n)
      bfv[n] = *(const bf16x8*)&sB[wc * 64 + n * 16 + lr][8 * lg];
#pragma unroll
    for (int m = 0; m < 4; ++m)
#pragma unroll
      for (int n = 0; n < 4; ++n)
        acc[m][n] = MFMA16(af[m], bfv[n], acc[m][n]);
    __syncthreads();

    aptr += 32;
    bptr += (size_t)32 * N;
  }

#pragma unroll
  for (int m = 0; m < 4; ++m) {
#pragma unroll
    for (int n = 0; n < 4; ++n) {
      const int colg = n0 + wc * 64 + n * 16 + lr;
      const float bv = bias[colg];
#pragma unroll
      for (int i = 0; i < 4; ++i) {
        const int row = m0 + wr * 64 + m * 16 + lg * 4 + i;
        Out[(size_t)row * N + colg] = acc[m][n][i] + bv;
      }
    }
  }
}

extern "C" void kernel_launch(void* const* d_in, const int* in_sizes, int n_in,
                              void* d_out, int out_size, void* d_ws,
                              size_t ws_size, hipStream_t stream) {
  const float* x     = (const float*)d_in[0];
  const float* w_qkv = (const float*)d_in[1];
  const float* b_qkv = (const float*)d_in[2];
  const float* w_out = (const float*)d_in[3];
  const float* b_out = (const float*)d_in[4];
  float* out = (float*)d_out;

  char* ws = (char*)d_ws;
  const size_t SZ = (size_t)8192 * 1024 * sizeof(bf16);  // 16 MB each
  bf16* Qb = (bf16*)(ws);           // [B*H][L][64]
  bf16* Kb = (bf16*)(ws + SZ);      // [B*H][L][64]
  bf16* Vt = (bf16*)(ws + 2 * SZ);  // [B*H][64][L]  (transposed V)
  bf16* Ab = (bf16*)(ws + 3 * SZ);  // attn out, [B*L][1024]

  gemm_qkv_kernel<<<dim3(24, 64), 256, 0, stream>>>(x, w_qkv, b_qkv, Qb, Kb, Vt);
  attn_kernel<<<dim3(2048), 256, 0, stream>>>(Qb, Kb, Vt, Ab);
  gemm_out_kernel<<<dim3(8, 64), 256, 0, stream>>>(Ab, w_out, b_out, out);
}

// Round 3
// 460.191 us; speedup vs baseline: 1.5465x; 1.2200x over previous
//
#include <hip/hip_runtime.h>

typedef __bf16 bf16;
typedef __attribute__((ext_vector_type(8))) __bf16 bf16x8;
typedef __attribute__((ext_vector_type(4))) __bf16 bf16x4;
typedef __attribute__((ext_vector_type(4))) float f32x4;

#define MFMA16(a, b, c) __builtin_amdgcn_mfma_f32_16x16x32_bf16((a), (b), (c), 0, 0, 0)

// Shapes: B=4, L=2048, DIM=1024, H=16, HD=64. M = B*L = 8192. K is always 1024.

static __device__ __forceinline__ bf16x8 cvt_f4x2(const float4 a, const float4 b) {
  bf16x8 r;
  r[0] = (bf16)a.x; r[1] = (bf16)a.y; r[2] = (bf16)a.z; r[3] = (bf16)a.w;
  r[4] = (bf16)b.x; r[5] = (bf16)b.y; r[6] = (bf16)b.z; r[7] = (bf16)b.w;
  return r;
}

// async global->LDS, 16B per lane. LDS dest must be linear (wave base + lane*16).
static __device__ __forceinline__ void gll16(const bf16* g, bf16* l) {
  __builtin_amdgcn_global_load_lds(
      (const __attribute__((address_space(1))) void*)g,
      (__attribute__((address_space(3))) void*)l, 16, 0, 0);
}

// ---------------------------------------------------------------------------
// Transpose+convert weights: W [1024][Nw] f32  ->  Wt [Nw][1024] bf16
// ---------------------------------------------------------------------------
__global__ __launch_bounds__(256) void conv_w_kernel(
    const float* __restrict__ W, bf16* __restrict__ Wt, int Nw) {
  __shared__ bf16 sT[64][72];  // [n][k], pad to kill write conflicts
  const int tid = threadIdx.x;
  const int n0 = blockIdx.x * 64, k0 = blockIdx.y * 64;
  const int kr = tid >> 4;           // 0..15
  const int c4 = (tid & 15) * 4;     // n-col
#pragma unroll
  for (int i = 0; i < 4; ++i) {
    const int k = kr + i * 16;
    const float4 w4 = *(const float4*)&W[(size_t)(k0 + k) * Nw + n0 + c4];
    sT[c4 + 0][k] = (bf16)w4.x;
    sT[c4 + 1][k] = (bf16)w4.y;
    sT[c4 + 2][k] = (bf16)w4.z;
    sT[c4 + 3][k] = (bf16)w4.w;
  }
  __syncthreads();
  const int r = tid >> 2;            // n-row 0..63
  const int c8 = (tid & 3) * 16;     // k-chunk
  *(bf16x8*)&Wt[(size_t)(n0 + r) * 1024 + k0 + c8] = *(const bf16x8*)&sT[r][c8];
  *(bf16x8*)&Wt[(size_t)(n0 + r) * 1024 + k0 + c8 + 8] =
      *(const bf16x8*)&sT[r][c8 + 8];
}

// ---------------------------------------------------------------------------
// GEMM1: qkv = X @ W + b. A (f32) reg-staged -> bf16 LDS; B (bf16 Wt[N][K])
// via global_load_lds. BM=BN=128, BK=64, 4 waves (2x2), 64x64 per wave.
// Epilogue scatters Q,K to [B*H][L][64]; V transposed to Vt[B*H][64][L].
// ---------------------------------------------------------------------------
__global__ __launch_bounds__(256) void gemm_qkv_kernel(
    const float* __restrict__ X, const bf16* __restrict__ Wt,
    const float* __restrict__ bias, bf16* __restrict__ Qb,
    bf16* __restrict__ Kb, bf16* __restrict__ Vt) {
  constexpr int K = 1024;
  __shared__ __align__(16) bf16 sA[128 * 64];
  __shared__ __align__(16) bf16 sB[128 * 64];
  const int tid = threadIdx.x;
  const int m0 = blockIdx.y * 128, n0 = blockIdx.x * 128;
  const int wid = tid >> 6, lane = tid & 63;
  const int wr = wid >> 1, wc = wid & 1;
  const int lg = lane >> 4, lr = lane & 15;

  const f32x4 fz = {0.f, 0.f, 0.f, 0.f};
  f32x4 acc[4][4];
#pragma unroll
  for (int m = 0; m < 4; ++m)
#pragma unroll
    for (int n = 0; n < 4; ++n) acc[m][n] = fz;

  for (int k0 = 0; k0 < K; k0 += 64) {
    // B: async GLL, linear [n][k] 128x64
#pragma unroll
    for (int s = 0; s < 4; ++s) {
      const int off = s * 2048 + tid * 8;
      const int row = off >> 6, col = off & 63;
      gll16(&Wt[(size_t)(n0 + row) * K + k0 + col], &sB[off]);
    }
    // A: f32 -> bf16 reg-staged, linear [m][k] 128x64
#pragma unroll
    for (int p = 0; p < 4; ++p) {
      const int g = tid + p * 256;       // 32B chunk index
      const int row = g >> 3, c8 = (g & 7) * 8;
      const float4* src = (const float4*)&X[(size_t)(m0 + row) * K + k0 + c8];
      const float4 u = src[0], w = src[1];
      *(bf16x8*)&sA[row * 64 + c8] = cvt_f4x2(u, w);
    }
    __syncthreads();

    bf16x8 af[2][4], bfv[2][4];
#pragma unroll
    for (int ks = 0; ks < 2; ++ks) {
#pragma unroll
      for (int m = 0; m < 4; ++m)
        af[ks][m] = *(const bf16x8*)&sA[(wr * 64 + m * 16 + lr) * 64 + ks * 32 + 8 * lg];
#pragma unroll
      for (int n = 0; n < 4; ++n)
        bfv[ks][n] = *(const bf16x8*)&sB[(wc * 64 + n * 16 + lr) * 64 + ks * 32 + 8 * lg];
    }
#pragma unroll
    for (int ks = 0; ks < 2; ++ks)
#pragma unroll
      for (int m = 0; m < 4; ++m)
#pragma unroll
        for (int n = 0; n < 4; ++n)
          acc[m][n] = MFMA16(af[ks][m], bfv[ks][n], acc[m][n]);
    __syncthreads();
  }

  if (n0 < 2048) {
    bf16* dst = (n0 < 1024) ? Qb : Kb;
#pragma unroll
    for (int m = 0; m < 4; ++m) {
#pragma unroll
      for (int n = 0; n < 4; ++n) {
        const int colg = n0 + wc * 64 + n * 16 + lr;
        const int col = colg & 1023;
        const int h = col >> 6, d = col & 63;
        const float bv = bias[colg];
#pragma unroll
        for (int i = 0; i < 4; ++i) {
          const int row = m0 + wr * 64 + m * 16 + lg * 4 + i;
          const int bb = row >> 11, ll = row & 2047;
          dst[((size_t)((bb * 16 + h) * 2048 + ll)) * 64 + d] =
              (bf16)(acc[m][n][i] + bv);
        }
      }
    }
  } else {
#pragma unroll
    for (int m = 0; m < 4; ++m) {
#pragma unroll
      for (int n = 0; n < 4; ++n) {
        const int colg = n0 + wc * 64 + n * 16 + lr;
        const int col = colg & 1023;
        const int h = col >> 6, d = col & 63;
        const float bv = bias[colg];
        const int row0 = m0 + wr * 64 + m * 16 + lg * 4;
        const int bb = row0 >> 11, ll0 = row0 & 2047;
        bf16x4 pk;
#pragma unroll
        for (int i = 0; i < 4; ++i) pk[i] = (bf16)(acc[m][n][i] + bv);
        *(bf16x4*)&Vt[((size_t)((bb * 16 + h) * 64 + d)) * 2048 + ll0] = pk;
      }
    }
  }
}

// ---------------------------------------------------------------------------
// Causal flash attention, swapped-QK^T, K-fragment ping-pong prefetch,
// defer-max (THR=8), maskless main loop + masked diagonal tile.
// Grid 2048: bh = id&63 (XCD-stable), qt = 31-(id>>6) heavy-first.
// ---------------------------------------------------------------------------
struct Kf { bf16x8 h[4][2]; };

static __device__ __forceinline__ void k_load(Kf& f, const bf16* Kbh, int kv0,
                                              int lg, int lr) {
#pragma unroll
  for (int sub = 0; sub < 4; ++sub) {
    const bf16* kr = Kbh + (size_t)(kv0 + sub * 16 + lr) * 64 + 8 * lg;
    f.h[sub][0] = *(const bf16x8*)kr;
    f.h[sub][1] = *(const bf16x8*)(kr + 32);
  }
}

static __device__ __forceinline__ void kv_compute(
    const Kf& f, const bf16* Vth, int kv0, bool masked, const bf16x8& qf0,
    const bf16x8& qf1, f32x4 o[4], float& m_, float& ssum, bf16* sPw, int lg,
    int lr, int qrow) {
  const f32x4 fz = {0.f, 0.f, 0.f, 0.f};
  // V loads issued first; softmax below hides their latency
  bf16x8 vf[4][2];
#pragma unroll
  for (int n = 0; n < 4; ++n)
#pragma unroll
    for (int c2 = 0; c2 < 2; ++c2)
      vf[n][c2] = *(const bf16x8*)&Vth[(size_t)(n * 16 + lr) * 2048 + kv0 +
                                       32 * c2 + 8 * lg];
  // S^T = K Q^T (Q pre-scaled): C row=kv=4lg+i, col=q=lr
  f32x4 s[4];
  __builtin_amdgcn_s_setprio(1);
#pragma unroll
  for (int sub = 0; sub < 4; ++sub) {
    f32x4 sc = MFMA16(f.h[sub][0], qf0, fz);
    s[sub] = MFMA16(f.h[sub][1], qf1, sc);
  }
  __builtin_amdgcn_s_setprio(0);

  float sv[16];
  float rm = -3e30f;
#pragma unroll
  for (int sub = 0; sub < 4; ++sub)
#pragma unroll
    for (int i = 0; i < 4; ++i) {
      float v = s[sub][i];
      if (masked) {
        const int kvg = kv0 + sub * 16 + lg * 4 + i;
        v = (kvg > qrow) ? -3e30f : v;
      }
      sv[sub * 4 + i] = v;
      rm = fmaxf(rm, v);
    }
  rm = fmaxf(rm, __shfl_xor(rm, 16));
  rm = fmaxf(rm, __shfl_xor(rm, 32));
  if (!__all(rm <= m_ + 8.f)) {  // T13 defer-max
    const float mn = fmaxf(m_, rm);
    const float corr = __expf(m_ - mn);
    ssum *= corr;
    m_ = mn;
    float cr[4];
#pragma unroll
    for (int i = 0; i < 4; ++i) cr[i] = __shfl(corr, 4 * lg + i);
#pragma unroll
    for (int n = 0; n < 4; ++n)
#pragma unroll
      for (int i = 0; i < 4; ++i) o[n][i] *= cr[i];
  }
  float rs = 0.f;
#pragma unroll
  for (int sub = 0; sub < 4; ++sub) {
    bf16x4 pk;
#pragma unroll
    for (int i = 0; i < 4; ++i) {
      const float p = __expf(sv[sub * 4 + i] - m_);
      rs += p;
      pk[i] = (bf16)p;
    }
    *(bf16x4*)&sPw[lr * 72 + 16 * sub + 4 * lg] = pk;
  }
  rs += __shfl_xor(rs, 16);
  rs += __shfl_xor(rs, 32);
  ssum += rs;
  // O += P V
  __builtin_amdgcn_s_setprio(1);
#pragma unroll
  for (int c2 = 0; c2 < 2; ++c2) {
    const bf16x8 pf = *(const bf16x8*)&sPw[lr * 72 + 32 * c2 + 8 * lg];
#pragma unroll
    for (int n = 0; n < 4; ++n) o[n] = MFMA16(pf, vf[n][c2], o[n]);
  }
  __builtin_amdgcn_s_setprio(0);
}

__global__ __launch_bounds__(256, 3) void attn_kernel(
    const bf16* __restrict__ Qb, const bf16* __restrict__ Kb,
    const bf16* __restrict__ Vt, bf16* __restrict__ O) {
  __shared__ __align__(16) bf16 sP[4][16][72];
  const int tid = threadIdx.x;
  const int qt = 31 - (int)(blockIdx.x >> 6);
  const int bh = blockIdx.x & 63;
  const int q0 = qt * 64;
  const int wid = tid >> 6, lane = tid & 63;
  const int lg = lane >> 4, lr = lane & 15;
  const bf16* Kbh = Kb + (size_t)bh * (2048 * 64);
  const bf16* Vth = Vt + (size_t)bh * (64 * 2048);
  bf16* sPw = &sP[wid][0][0];

  // Q fragments, pre-scaled by 1/8 (exact in bf16)
  const int qrow = q0 + wid * 16 + lr;
  const bf16* qp = Qb + (size_t)bh * (2048 * 64) + (size_t)qrow * 64 + 8 * lg;
  bf16x8 qf0 = *(const bf16x8*)qp;
  bf16x8 qf1 = *(const bf16x8*)(qp + 32);
#pragma unroll
  for (int j = 0; j < 8; ++j) {
    qf0[j] = (bf16)((float)qf0[j] * 0.125f);
    qf1[j] = (bf16)((float)qf1[j] * 0.125f);
  }

  const f32x4 fz = {0.f, 0.f, 0.f, 0.f};
  f32x4 o[4];
#pragma unroll
  for (int n = 0; n < 4; ++n) o[n] = fz;
  float m_ = -1e30f, ssum = 0.f;

  Kf fA, fB;
  k_load(fA, Kbh, 0, lg, lr);
  int t = 0;
  while (t + 2 <= qt) {
    k_load(fB, Kbh, (t + 1) * 64, lg, lr);
    kv_compute(fA, Vth, t * 64, false, qf0, qf1, o, m_, ssum, sPw, lg, lr, qrow);
    k_load(fA, Kbh, (t + 2) * 64, lg, lr);
    kv_compute(fB, Vth, (t + 1) * 64, false, qf0, qf1, o, m_, ssum, sPw, lg, lr, qrow);
    t += 2;
  }
  if (t < qt) {  // one unmasked + diagonal
    k_load(fB, Kbh, qt * 64, lg, lr);
    kv_compute(fA, Vth, t * 64, false, qf0, qf1, o, m_, ssum, sPw, lg, lr, qrow);
    kv_compute(fB, Vth, qt * 64, true, qf0, qf1, o, m_, ssum, sPw, lg, lr, qrow);
  } else {
    kv_compute(fA, Vth, qt * 64, true, qf0, qf1, o, m_, ssum, sPw, lg, lr, qrow);
  }

  const float rinv = 1.f / ssum;
  float rv[4];
#pragma unroll
  for (int i = 0; i < 4; ++i) rv[i] = __shfl(rinv, 4 * lg + i);
  const int b = bh >> 4, h = bh & 15;
#pragma unroll
  for (int n = 0; n < 4; ++n)
#pragma unroll
    for (int i = 0; i < 4; ++i) {
      const int q = q0 + wid * 16 + 4 * lg + i;
      O[((size_t)(b * 2048 + q)) * 1024 + h * 64 + n * 16 + lr] =
          (bf16)(o[n][i] * rv[i]);
    }
}

// ---------------------------------------------------------------------------
// GEMM2: out = Ab @ w_out + b. Both sides bf16 via global_load_lds.
// ---------------------------------------------------------------------------
__global__ __launch_bounds__(256) void gemm_out_kernel(
    const bf16* __restrict__ A, const bf16* __restrict__ Wt,
    const float* __restrict__ bias, float* __restrict__ Out) {
  constexpr int K = 1024, N = 1024;
  __shared__ __align__(16) bf16 sA[128 * 64];
  __shared__ __align__(16) bf16 sB[128 * 64];
  const int tid = threadIdx.x;
  const int m0 = blockIdx.y * 128, n0 = blockIdx.x * 128;
  const int wid = tid >> 6, lane = tid & 63;
  const int wr = wid >> 1, wc = wid & 1;
  const int lg = lane >> 4, lr = lane & 15;

  const f32x4 fz = {0.f, 0.f, 0.f, 0.f};
  f32x4 acc[4][4];
#pragma unroll
  for (int m = 0; m < 4; ++m)
#pragma unroll
    for (int n = 0; n < 4; ++n) acc[m][n] = fz;

  for (int k0 = 0; k0 < K; k0 += 64) {
#pragma unroll
    for (int s = 0; s < 4; ++s) {
      const int off = s * 2048 + tid * 8;
      const int row = off >> 6, col = off & 63;
      gll16(&A[(size_t)(m0 + row) * K + k0 + col], &sA[off]);
      gll16(&Wt[(size_t)(n0 + row) * K + k0 + col], &sB[off]);
    }
    __syncthreads();

    bf16x8 af[2][4], bfv[2][4];
#pragma unroll
    for (int ks = 0; ks < 2; ++ks) {
#pragma unroll
      for (int m = 0; m < 4; ++m)
        af[ks][m] = *(const bf16x8*)&sA[(wr * 64 + m * 16 + lr) * 64 + ks * 32 + 8 * lg];
#pragma unroll
      for (int n = 0; n < 4; ++n)
        bfv[ks][n] = *(const bf16x8*)&sB[(wc * 64 + n * 16 + lr) * 64 + ks * 32 + 8 * lg];
    }
#pragma unroll
    for (int ks = 0; ks < 2; ++ks)
#pragma unroll
      for (int m = 0; m < 4; ++m)
#pragma unroll
        for (int n = 0; n < 4; ++n)
          acc[m][n] = MFMA16(af[ks][m], bfv[ks][n], acc[m][n]);
    __syncthreads();
  }

#pragma unroll
  for (int m = 0; m < 4; ++m) {
#pragma unroll
    for (int n = 0; n < 4; ++n) {
      const int colg = n0 + wc * 64 + n * 16 + lr;
      const float bv = bias[colg];
#pragma unroll
      for (int i = 0; i < 4; ++i) {
        const int row = m0 + wr * 64 + m * 16 + lg * 4 + i;
        Out[(size_t)row * N + colg] = acc[m][n][i] + bv;
      }
    }
  }
}

extern "C" void kernel_launch(void* const* d_in, const int* in_sizes, int n_in,
                              void* d_out, int out_size, void* d_ws,
                              size_t ws_size, hipStream_t stream) {
  const float* x     = (const float*)d_in[0];
  const float* w_qkv = (const float*)d_in[1];
  const float* b_qkv = (const float*)d_in[2];
  const float* w_out = (const float*)d_in[3];
  const float* b_out = (const float*)d_in[4];
  float* out = (float*)d_out;

  // Workspace layout (64 MB proven budget), lifetimes packed:
  //   [0,16)  Qb           [GEMM1..attn]   / Wt2 (2MB)  [conv2..GEMM2]
  //   [16,32) Kb           [GEMM1..attn]
  //   [32,48) Vt           [GEMM1..attn]
  //   [48,54) Wt1 (6MB)    [conv1..GEMM1]
  //   [48,64) Ab  (16MB)   [attn..GEMM2]
  char* ws = (char*)d_ws;
  const size_t MB = 1024 * 1024;
  bf16* Qb  = (bf16*)(ws);
  bf16* Kb  = (bf16*)(ws + 16 * MB);
  bf16* Vt  = (bf16*)(ws + 32 * MB);
  bf16* Wt1 = (bf16*)(ws + 48 * MB);
  bf16* Ab  = (bf16*)(ws + 48 * MB);
  bf16* Wt2 = (bf16*)(ws);  // overwrites dead Qb after attn

  conv_w_kernel<<<dim3(48, 16), 256, 0, stream>>>(w_qkv, Wt1, 3072);
  gemm_qkv_kernel<<<dim3(24, 64), 256, 0, stream>>>(x, Wt1, b_qkv, Qb, Kb, Vt);
  attn_kernel<<<dim3(2048), 256, 0, stream>>>(Qb, Kb, Vt, Ab);
  conv_w_kernel<<<dim3(16, 16), 256, 0, stream>>>(w_out, Wt2, 1024);
  gemm_out_kernel<<<dim3(8, 64), 256, 0, stream>>>(Ab, Wt2, b_out, out);
}

// Round 4
// 326.901 us; speedup vs baseline: 2.1771x; 1.4077x over previous
//
#include <hip/hip_runtime.h>

typedef __bf16 bf16;
typedef __attribute__((ext_vector_type(8))) __bf16 bf16x8;
typedef __attribute__((ext_vector_type(4))) __bf16 bf16x4;
typedef __attribute__((ext_vector_type(4))) float f32x4;

#define MFMA16(a, b, c) __builtin_amdgcn_mfma_f32_16x16x32_bf16((a), (b), (c), 0, 0, 0)

// Shapes: B=4, L=2048, DIM=1024, H=16, HD=64. M = B*L = 8192. K always 1024.

static __device__ __forceinline__ bf16x8 cvt_f4x2(const float4 a, const float4 b) {
  bf16x8 r;
  r[0] = (bf16)a.x; r[1] = (bf16)a.y; r[2] = (bf16)a.z; r[3] = (bf16)a.w;
  r[4] = (bf16)b.x; r[5] = (bf16)b.y; r[6] = (bf16)b.z; r[7] = (bf16)b.w;
  return r;
}

static __device__ __forceinline__ void gll16(const bf16* g, bf16* l) {
  __builtin_amdgcn_global_load_lds(
      (const __attribute__((address_space(1))) void*)g,
      (__attribute__((address_space(3))) void*)l, 16, 0, 0);
}

// ---------------------------------------------------------------------------
// conv_x: X f32 [8192][1024] -> Xb bf16 (same layout)
// ---------------------------------------------------------------------------
__global__ __launch_bounds__(256) void conv_x_kernel(const float* __restrict__ X,
                                                     bf16* __restrict__ Xb) {
  const size_t i = ((size_t)blockIdx.x * 256 + threadIdx.x) * 16;
  const float4* s = (const float4*)&X[i];
  *(bf16x8*)&Xb[i] = cvt_f4x2(s[0], s[1]);
  *(bf16x8*)&Xb[i + 8] = cvt_f4x2(s[2], s[3]);
}

// ---------------------------------------------------------------------------
// conv_w: W [1024][Nw] f32 -> Wt [Nw][1024] bf16 (transpose+convert)
// ---------------------------------------------------------------------------
__global__ __launch_bounds__(256) void conv_w_kernel(
    const float* __restrict__ W, bf16* __restrict__ Wt, int Nw) {
  __shared__ bf16 sT[64][72];
  const int tid = threadIdx.x;
  const int n0 = blockIdx.x * 64, k0 = blockIdx.y * 64;
  const int kr = tid >> 4;
  const int c4 = (tid & 15) * 4;
#pragma unroll
  for (int i = 0; i < 4; ++i) {
    const int k = kr + i * 16;
    const float4 w4 = *(const float4*)&W[(size_t)(k0 + k) * Nw + n0 + c4];
    sT[c4 + 0][k] = (bf16)w4.x;
    sT[c4 + 1][k] = (bf16)w4.y;
    sT[c4 + 2][k] = (bf16)w4.z;
    sT[c4 + 3][k] = (bf16)w4.w;
  }
  __syncthreads();
  const int r = tid >> 2;
  const int c8 = (tid & 3) * 16;
  *(bf16x8*)&Wt[(size_t)(n0 + r) * 1024 + k0 + c8] = *(const bf16x8*)&sT[r][c8];
  *(bf16x8*)&Wt[(size_t)(n0 + r) * 1024 + k0 + c8 + 8] =
      *(const bf16x8*)&sT[r][c8 + 8];
}

// ---------------------------------------------------------------------------
// QKV scatter epilogue (shared by both GEMM1 variants)
// ---------------------------------------------------------------------------
static __device__ __forceinline__ void qkv_epilogue(
    f32x4 acc[4][4], const float* bias, bf16* Qb, bf16* Kb, bf16* Vt, int m0,
    int n0, int wr, int wc, int lg, int lr) {
  if (n0 < 2048) {
    bf16* dst = (n0 < 1024) ? Qb : Kb;
#pragma unroll
    for (int m = 0; m < 4; ++m) {
#pragma unroll
      for (int n = 0; n < 4; ++n) {
        const int colg = n0 + wc * 64 + n * 16 + lr;
        const int col = colg & 1023;
        const int h = col >> 6, d = col & 63;
        const float bv = bias[colg];
#pragma unroll
        for (int i = 0; i < 4; ++i) {
          const int row = m0 + wr * 64 + m * 16 + lg * 4 + i;
          const int bb = row >> 11, ll = row & 2047;
          dst[((size_t)((bb * 16 + h) * 2048 + ll)) * 64 + d] =
              (bf16)(acc[m][n][i] + bv);
        }
      }
    }
  } else {
#pragma unroll
    for (int m = 0; m < 4; ++m) {
#pragma unroll
      for (int n = 0; n < 4; ++n) {
        const int colg = n0 + wc * 64 + n * 16 + lr;
        const int col = colg & 1023;
        const int h = col >> 6, d = col & 63;
        const float bv = bias[colg];
        const int row0 = m0 + wr * 64 + m * 16 + lg * 4;
        const int bb = row0 >> 11, ll0 = row0 & 2047;
        bf16x4 pk;
#pragma unroll
        for (int i = 0; i < 4; ++i) pk[i] = (bf16)(acc[m][n][i] + bv);
        *(bf16x4*)&Vt[((size_t)((bb * 16 + h) * 64 + d)) * 2048 + ll0] = pk;
      }
    }
  }
}

// ---------------------------------------------------------------------------
// GEMM1 (big-ws path): both operands bf16 via global_load_lds.
// ---------------------------------------------------------------------------
__global__ __launch_bounds__(256) void gemm_qkv_bf16_kernel(
    const bf16* __restrict__ Xb, const bf16* __restrict__ Wt,
    const float* __restrict__ bias, bf16* __restrict__ Qb,
    bf16* __restrict__ Kb, bf16* __restrict__ Vt) {
  constexpr int K = 1024;
  __shared__ __align__(16) bf16 sA[128 * 64];
  __shared__ __align__(16) bf16 sB[128 * 64];
  const int tid = threadIdx.x;
  const int m0 = blockIdx.y * 128, n0 = blockIdx.x * 128;
  const int wid = tid >> 6, lane = tid & 63;
  const int wr = wid >> 1, wc = wid & 1;
  const int lg = lane >> 4, lr = lane & 15;

  const f32x4 fz = {0.f, 0.f, 0.f, 0.f};
  f32x4 acc[4][4];
#pragma unroll
  for (int m = 0; m < 4; ++m)
#pragma unroll
    for (int n = 0; n < 4; ++n) acc[m][n] = fz;

  for (int k0 = 0; k0 < K; k0 += 64) {
#pragma unroll
    for (int s = 0; s < 4; ++s) {
      const int off = s * 2048 + tid * 8;
      const int row = off >> 6, col = off & 63;
      gll16(&Xb[(size_t)(m0 + row) * K + k0 + col], &sA[off]);
      gll16(&Wt[(size_t)(n0 + row) * K + k0 + col], &sB[off]);
    }
    __syncthreads();

    bf16x8 af[2][4], bfv[2][4];
#pragma unroll
    for (int ks = 0; ks < 2; ++ks) {
#pragma unroll
      for (int m = 0; m < 4; ++m)
        af[ks][m] = *(const bf16x8*)&sA[(wr * 64 + m * 16 + lr) * 64 + ks * 32 + 8 * lg];
#pragma unroll
      for (int n = 0; n < 4; ++n)
        bfv[ks][n] = *(const bf16x8*)&sB[(wc * 64 + n * 16 + lr) * 64 + ks * 32 + 8 * lg];
    }
#pragma unroll
    for (int ks = 0; ks < 2; ++ks)
#pragma unroll
      for (int m = 0; m < 4; ++m)
#pragma unroll
        for (int n = 0; n < 4; ++n)
          acc[m][n] = MFMA16(af[ks][m], bfv[ks][n], acc[m][n]);
    __syncthreads();
  }
  qkv_epilogue(acc, bias, Qb, Kb, Vt, m0, n0, wr, wc, lg, lr);
}

// ---------------------------------------------------------------------------
// GEMM1 (fallback): A f32 reg-staged, B via gll (round-3 version).
// ---------------------------------------------------------------------------
__global__ __launch_bounds__(256) void gemm_qkv_kernel(
    const float* __restrict__ X, const bf16* __restrict__ Wt,
    const float* __restrict__ bias, bf16* __restrict__ Qb,
    bf16* __restrict__ Kb, bf16* __restrict__ Vt) {
  constexpr int K = 1024;
  __shared__ __align__(16) bf16 sA[128 * 64];
  __shared__ __align__(16) bf16 sB[128 * 64];
  const int tid = threadIdx.x;
  const int m0 = blockIdx.y * 128, n0 = blockIdx.x * 128;
  const int wid = tid >> 6, lane = tid & 63;
  const int wr = wid >> 1, wc = wid & 1;
  const int lg = lane >> 4, lr = lane & 15;

  const f32x4 fz = {0.f, 0.f, 0.f, 0.f};
  f32x4 acc[4][4];
#pragma unroll
  for (int m = 0; m < 4; ++m)
#pragma unroll
    for (int n = 0; n < 4; ++n) acc[m][n] = fz;

  for (int k0 = 0; k0 < K; k0 += 64) {
#pragma unroll
    for (int s = 0; s < 4; ++s) {
      const int off = s * 2048 + tid * 8;
      const int row = off >> 6, col = off & 63;
      gll16(&Wt[(size_t)(n0 + row) * K + k0 + col], &sB[off]);
    }
#pragma unroll
    for (int p = 0; p < 4; ++p) {
      const int g = tid + p * 256;
      const int row = g >> 3, c8 = (g & 7) * 8;
      const float4* src = (const float4*)&X[(size_t)(m0 + row) * K + k0 + c8];
      const float4 u = src[0], w = src[1];
      *(bf16x8*)&sA[row * 64 + c8] = cvt_f4x2(u, w);
    }
    __syncthreads();

    bf16x8 af[2][4], bfv[2][4];
#pragma unroll
    for (int ks = 0; ks < 2; ++ks) {
#pragma unroll
      for (int m = 0; m < 4; ++m)
        af[ks][m] = *(const bf16x8*)&sA[(wr * 64 + m * 16 + lr) * 64 + ks * 32 + 8 * lg];
#pragma unroll
      for (int n = 0; n < 4; ++n)
        bfv[ks][n] = *(const bf16x8*)&sB[(wc * 64 + n * 16 + lr) * 64 + ks * 32 + 8 * lg];
    }
#pragma unroll
    for (int ks = 0; ks < 2; ++ks)
#pragma unroll
      for (int m = 0; m < 4; ++m)
#pragma unroll
        for (int n = 0; n < 4; ++n)
          acc[m][n] = MFMA16(af[ks][m], bfv[ks][n], acc[m][n]);
    __syncthreads();
  }
  qkv_epilogue(acc, bias, Qb, Kb, Vt, m0, n0, wr, wc, lg, lr);
}

// ---------------------------------------------------------------------------
// Causal flash attention. QBLK=128 (wave owns 2x16 q-rows), KVBLK=64.
// K/V staged in LDS via global_load_lds, double-buffered, counted vmcnt(4).
// T2 XOR-swizzle (elem ^= (row&7)<<3) applied via pre-swizzled global source;
// all b128 LDS reads conflict-free. Swapped QK^T -> per-lane softmax.
// Grid 1024: bh = id&63 (XCD-aligned), qb = 15-(id>>6) heavy-first.
// ---------------------------------------------------------------------------
#define ATTN_FULL 0
#define ATTN_MASK 1
#define ATTN_SKIP 2

__global__ __launch_bounds__(256, 3) void attn_kernel(
    const bf16* __restrict__ Qb, const bf16* __restrict__ Kb,
    const bf16* __restrict__ Vt, bf16* __restrict__ O) {
  __shared__ __align__(16) bf16 sK[2][64 * 64];
  __shared__ __align__(16) bf16 sV[2][64 * 64];
  __shared__ __align__(16) bf16 sP[4][16 * 72];
  const int tid = threadIdx.x;
  const int qb = 15 - (int)(blockIdx.x >> 6);
  const int bh = blockIdx.x & 63;
  const int q0 = qb * 128;
  const int nt = 2 * qb + 2;
  const int wid = tid >> 6, lane = tid & 63;
  const int lg = lane >> 4, lr = lane & 15;
  const bf16* Kbh = Kb + (size_t)bh * (2048 * 64);
  const bf16* Vth = Vt + (size_t)bh * (64 * 2048);
  bf16* sPw = &sP[wid][0];
  const int swz = (lr & 7) << 3;  // element-index XOR for all frag reads

  // Q fragments for both q-halves, pre-scaled by 1/8 (exact in bf16)
  const int qrow0 = q0 + wid * 16 + lr;
  const int qrow1 = qrow0 + 64;
  bf16x8 qf[2][2];
#pragma unroll
  for (int h = 0; h < 2; ++h) {
    const bf16* qp =
        Qb + (size_t)bh * (2048 * 64) + (size_t)(qrow0 + 64 * h) * 64 + 8 * lg;
    qf[h][0] = *(const bf16x8*)qp;
    qf[h][1] = *(const bf16x8*)(qp + 32);
#pragma unroll
    for (int j = 0; j < 8; ++j) {
      qf[h][0][j] = (bf16)((float)qf[h][0][j] * 0.125f);
      qf[h][1][j] = (bf16)((float)qf[h][1][j] * 0.125f);
    }
  }

  // Staging source coords (pre-swizzled so LDS write stays linear).
  const int pe = tid * 8;                       // elem offset within 2K half
  const int srow0 = pe >> 6;                    // rows 0..31 (pass A)
  const int scol0 = (pe & 63) ^ ((srow0 & 7) << 3);
  const int srow1 = srow0 + 32;                 // rows 32..63 (pass B)
  const int scol1 = (pe & 63) ^ ((srow1 & 7) << 3);

  const f32x4 fz = {0.f, 0.f, 0.f, 0.f};
  f32x4 o[2][4];
#pragma unroll
  for (int h = 0; h < 2; ++h)
#pragma unroll
    for (int n = 0; n < 4; ++n) o[h][n] = fz;
  float m_[2] = {-1e30f, -1e30f}, ssum[2] = {0.f, 0.f};

#define STAGE(buf, kv0_)                                                      \
  {                                                                           \
    const int kv0s = (kv0_);                                                  \
    gll16(&Kbh[(size_t)(kv0s + srow0) * 64 + scol0], &sK[buf][pe]);           \
    gll16(&Kbh[(size_t)(kv0s + srow1) * 64 + scol1], &sK[buf][2048 + pe]);    \
    gll16(&Vth[(size_t)srow0 * 2048 + kv0s + scol0], &sV[buf][pe]);           \
    gll16(&Vth[(size_t)srow1 * 2048 + kv0s + scol1], &sV[buf][2048 + pe]);    \
  }

  STAGE(0, 0);

  for (int t = 0; t < nt; ++t) {
    const int buf = t & 1;
    const int kv0 = t * 64;
    const int mode0 = (t < nt - 2) ? ATTN_FULL : (t == nt - 2 ? ATTN_MASK : ATTN_SKIP);
    const int mode1 = (t < nt - 1) ? ATTN_FULL : ATTN_MASK;

    __builtin_amdgcn_s_barrier();  // all waves done reading buf^1 (tile t-1)
    if (t + 1 < nt) {
      STAGE(buf ^ 1, kv0 + 64);
      asm volatile("s_waitcnt vmcnt(4)" ::: "memory");  // tile t landed
    } else {
      asm volatile("s_waitcnt vmcnt(0)" ::: "memory");
    }
    __builtin_amdgcn_s_barrier();  // tile t visible to all waves

    const bf16* sKb = sK[buf];
    const bf16* sVb = sV[buf];

    // S^T = K Q^T for both halves (K frags loaded once)
    f32x4 s0[4], s1[4];
    __builtin_amdgcn_s_setprio(1);
#pragma unroll
    for (int sub = 0; sub < 4; ++sub) {
      const int e = ((sub * 16 + lr) * 64 + 8 * lg) ^ swz;
      const bf16x8 kf0 = *(const bf16x8*)&sKb[e];
      const bf16x8 kf1 = *(const bf16x8*)&sKb[e ^ 32];
      if (mode0 != ATTN_SKIP) {
        f32x4 sc = MFMA16(kf0, qf[0][0], fz);
        s0[sub] = MFMA16(kf1, qf[0][1], sc);
      }
      f32x4 sc = MFMA16(kf0, qf[1][0], fz);
      s1[sub] = MFMA16(kf1, qf[1][1], sc);
    }
    __builtin_amdgcn_s_setprio(0);

    // V fragments (shared by both halves)
    bf16x8 vf[4][2];
#pragma unroll
    for (int n = 0; n < 4; ++n)
#pragma unroll
      for (int c2 = 0; c2 < 2; ++c2)
        vf[n][c2] = *(const bf16x8*)&sVb[(((n * 16 + lr) * 64 + c2 * 32 + 8 * lg)) ^ swz];

#pragma unroll
    for (int h = 0; h < 2; ++h) {
      const int mode = h ? mode1 : mode0;
      if (mode == ATTN_SKIP) continue;
      const int qrow = h ? qrow1 : qrow0;
      f32x4* sh = h ? s1 : s0;

      float sv[16];
      float rm = -3e30f;
#pragma unroll
      for (int sub = 0; sub < 4; ++sub)
#pragma unroll
        for (int i = 0; i < 4; ++i) {
          float v = sh[sub][i];
          if (mode == ATTN_MASK) {
            const int kvg = kv0 + sub * 16 + lg * 4 + i;
            v = (kvg > qrow) ? -3e30f : v;
          }
          sv[sub * 4 + i] = v;
          rm = fmaxf(rm, v);
        }
      rm = fmaxf(rm, __shfl_xor(rm, 16));
      rm = fmaxf(rm, __shfl_xor(rm, 32));
      if (!__all(rm <= m_[h] + 8.f)) {  // T13 defer-max
        const float mn = fmaxf(m_[h], rm);
        const float corr = __expf(m_[h] - mn);
        ssum[h] *= corr;
        m_[h] = mn;
        float cr[4];
#pragma unroll
        for (int i = 0; i < 4; ++i) cr[i] = __shfl(corr, 4 * lg + i);
#pragma unroll
        for (int n = 0; n < 4; ++n)
#pragma unroll
          for (int i = 0; i < 4; ++i) o[h][n][i] *= cr[i];
      }
      float rs = 0.f;
#pragma unroll
      for (int sub = 0; sub < 4; ++sub) {
        bf16x4 pk;
#pragma unroll
        for (int i = 0; i < 4; ++i) {
          const float p = __expf(sv[sub * 4 + i] - m_[h]);
          rs += p;
          pk[i] = (bf16)p;
        }
        *(bf16x4*)&sPw[lr * 72 + 16 * sub + 4 * lg] = pk;
      }
      rs += __shfl_xor(rs, 16);
      rs += __shfl_xor(rs, 32);
      ssum[h] += rs;
      __builtin_amdgcn_s_setprio(1);
#pragma unroll
      for (int c2 = 0; c2 < 2; ++c2) {
        const bf16x8 pf = *(const bf16x8*)&sPw[lr * 72 + 32 * c2 + 8 * lg];
#pragma unroll
        for (int n = 0; n < 4; ++n) o[h][n] = MFMA16(pf, vf[n][c2], o[h][n]);
      }
      __builtin_amdgcn_s_setprio(0);
    }
  }
#undef STAGE

  const int b = bh >> 4, hh = bh & 15;
#pragma unroll
  for (int h = 0; h < 2; ++h) {
    const float rinv = 1.f / ssum[h];
    float rv[4];
#pragma unroll
    for (int i = 0; i < 4; ++i) rv[i] = __shfl(rinv, 4 * lg + i);
#pragma unroll
    for (int n = 0; n < 4; ++n)
#pragma unroll
      for (int i = 0; i < 4; ++i) {
        const int q = q0 + 64 * h + wid * 16 + 4 * lg + i;
        O[((size_t)(b * 2048 + q)) * 1024 + hh * 64 + n * 16 + lr] =
            (bf16)(o[h][n][i] * rv[i]);
      }
  }
}

// ---------------------------------------------------------------------------
// GEMM2: out = Ab @ w_out + b. Both sides bf16 via global_load_lds.
// ---------------------------------------------------------------------------
__global__ __launch_bounds__(256) void gemm_out_kernel(
    const bf16* __restrict__ A, const bf16* __restrict__ Wt,
    const float* __restrict__ bias, float* __restrict__ Out) {
  constexpr int K = 1024, N = 1024;
  __shared__ __align__(16) bf16 sA[128 * 64];
  __shared__ __align__(16) bf16 sB[128 * 64];
  const int tid = threadIdx.x;
  const int m0 = blockIdx.y * 128, n0 = blockIdx.x * 128;
  const int wid = tid >> 6, lane = tid & 63;
  const int wr = wid >> 1, wc = wid & 1;
  const int lg = lane >> 4, lr = lane & 15;

  const f32x4 fz = {0.f, 0.f, 0.f, 0.f};
  f32x4 acc[4][4];
#pragma unroll
  for (int m = 0; m < 4; ++m)
#pragma unroll
    for (int n = 0; n < 4; ++n) acc[m][n] = fz;

  for (int k0 = 0; k0 < K; k0 += 64) {
#pragma unroll
    for (int s = 0; s < 4; ++s) {
      const int off = s * 2048 + tid * 8;
      const int row = off >> 6, col = off & 63;
      gll16(&A[(size_t)(m0 + row) * K + k0 + col], &sA[off]);
      gll16(&Wt[(size_t)(n0 + row) * K + k0 + col], &sB[off]);
    }
    __syncthreads();

    bf16x8 af[2][4], bfv[2][4];
#pragma unroll
    for (int ks = 0; ks < 2; ++ks) {
#pragma unroll
      for (int m = 0; m < 4; ++m)
        af[ks][m] = *(const bf16x8*)&sA[(wr * 64 + m * 16 + lr) * 64 + ks * 32 + 8 * lg];
#pragma unroll
      for (int n = 0; n < 4; ++n)
        bfv[ks][n] = *(const bf16x8*)&sB[(wc * 64 + n * 16 + lr) * 64 + ks * 32 + 8 * lg];
    }
#pragma unroll
    for (int ks = 0; ks < 2; ++ks)
#pragma unroll
      for (int m = 0; m < 4; ++m)
#pragma unroll
        for (int n = 0; n < 4; ++n)
          acc[m][n] = MFMA16(af[ks][m], bfv[ks][n], acc[m][n]);
    __syncthreads();
  }

#pragma unroll
  for (int m = 0; m < 4; ++m) {
#pragma unroll
    for (int n = 0; n < 4; ++n) {
      const int colg = n0 + wc * 64 + n * 16 + lr;
      const float bv = bias[colg];
#pragma unroll
      for (int i = 0; i < 4; ++i) {
        const int row = m0 + wr * 64 + m * 16 + lg * 4 + i;
        Out[(size_t)row * N + colg] = acc[m][n][i] + bv;
      }
    }
  }
}

extern "C" void kernel_launch(void* const* d_in, const int* in_sizes, int n_in,
                              void* d_out, int out_size, void* d_ws,
                              size_t ws_size, hipStream_t stream) {
  const float* x     = (const float*)d_in[0];
  const float* w_qkv = (const float*)d_in[1];
  const float* b_qkv = (const float*)d_in[2];
  const float* w_out = (const float*)d_in[3];
  const float* b_out = (const float*)d_in[4];
  float* out = (float*)d_out;

  char* ws = (char*)d_ws;
  const size_t MB = 1024 * 1024;

  if (ws_size >= 70 * MB) {
    // Big-ws layout:
    //   [0,16)  Xb (conv_x..GEMM1)  -> Ab (attn..GEMM2)
    //   [16,22) Wt1 (conv_w..GEMM1) -> Wt2 at [16,18) (conv2..GEMM2)
    //   [22,38) Qb  [38,54) Kb  [54,70) Vt   (GEMM1..attn)
    bf16* Xb  = (bf16*)(ws);
    bf16* Wt1 = (bf16*)(ws + 16 * MB);
    bf16* Qb  = (bf16*)(ws + 22 * MB);
    bf16* Kb  = (bf16*)(ws + 38 * MB);
    bf16* Vt  = (bf16*)(ws + 54 * MB);
    bf16* Ab  = (bf16*)(ws);
    bf16* Wt2 = (bf16*)(ws + 16 * MB);

    conv_x_kernel<<<dim3(2048), 256, 0, stream>>>(x, Xb);
    conv_w_kernel<<<dim3(48, 16), 256, 0, stream>>>(w_qkv, Wt1, 3072);
    gemm_qkv_bf16_kernel<<<dim3(24, 64), 256, 0, stream>>>(Xb, Wt1, b_qkv, Qb, Kb, Vt);
    attn_kernel<<<dim3(1024), 256, 0, stream>>>(Qb, Kb, Vt, Ab);
    conv_w_kernel<<<dim3(16, 16), 256, 0, stream>>>(w_out, Wt2, 1024);
    gemm_out_kernel<<<dim3(8, 64), 256, 0, stream>>>(Ab, Wt2, b_out, out);
  } else {
    // Fallback 64 MB layout (round-3):
    bf16* Qb  = (bf16*)(ws);
    bf16* Kb  = (bf16*)(ws + 16 * MB);
    bf16* Vt  = (bf16*)(ws + 32 * MB);
    bf16* Wt1 = (bf16*)(ws + 48 * MB);
    bf16* Ab  = (bf16*)(ws + 48 * MB);
    bf16* Wt2 = (bf16*)(ws);

    conv_w_kernel<<<dim3(48, 16), 256, 0, stream>>>(w_qkv, Wt1, 3072);
    gemm_qkv_kernel<<<dim3(24, 64), 256, 0, stream>>>(x, Wt1, b_qkv, Qb, Kb, Vt);
    attn_kernel<<<dim3(1024), 256, 0, stream>>>(Qb, Kb, Vt, Ab);
    conv_w_kernel<<<dim3(16, 16), 256, 0, stream>>>(w_out, Wt2, 1024);
    gemm_out_kernel<<<dim3(8, 64), 256, 0, stream>>>(Ab, Wt2, b_out, out);
  }
}

// Round 5
// 326.832 us; speedup vs baseline: 2.1776x; 1.0002x over previous
//
#include <hip/hip_runtime.h>

typedef __bf16 bf16;
typedef __attribute__((ext_vector_type(8))) __bf16 bf16x8;
typedef __attribute__((ext_vector_type(4))) __bf16 bf16x4;
typedef __attribute__((ext_vector_type(4))) float f32x4;

#define MFMA16(a, b, c) __builtin_amdgcn_mfma_f32_16x16x32_bf16((a), (b), (c), 0, 0, 0)

#if __has_builtin(__builtin_amdgcn_exp2f)
#define EXP2(x) __builtin_amdgcn_exp2f(x)
#else
#define EXP2(x) exp2f(x)
#endif

// Shapes: B=4, L=2048, DIM=1024, H=16, HD=64. M = B*L = 8192. K always 1024.

static __device__ __forceinline__ bf16x8 cvt_f4x2(const float4 a, const float4 b) {
  bf16x8 r;
  r[0] = (bf16)a.x; r[1] = (bf16)a.y; r[2] = (bf16)a.z; r[3] = (bf16)a.w;
  r[4] = (bf16)b.x; r[5] = (bf16)b.y; r[6] = (bf16)b.z; r[7] = (bf16)b.w;
  return r;
}

static __device__ __forceinline__ void gll16(const bf16* g, bf16* l) {
  __builtin_amdgcn_global_load_lds(
      (const __attribute__((address_space(1))) void*)g,
      (__attribute__((address_space(3))) void*)l, 16, 0, 0);
}

// ---------------------------------------------------------------------------
// Merged conversions: blocks [0,2048) convert X f32->bf16; blocks [2048,2816)
// transpose+convert w_qkv [1024][3072] -> Wt1 [3072][1024] bf16.
// ---------------------------------------------------------------------------
__global__ __launch_bounds__(256) void conv_all_kernel(
    const float* __restrict__ X, bf16* __restrict__ Xb,
    const float* __restrict__ W1, bf16* __restrict__ Wt1) {
  __shared__ bf16 sT[64][72];
  const int bid = blockIdx.x;
  const int tid = threadIdx.x;
  if (bid < 2048) {
    const size_t i = ((size_t)bid * 256 + tid) * 16;
    const float4* s = (const float4*)&X[i];
    *(bf16x8*)&Xb[i] = cvt_f4x2(s[0], s[1]);
    *(bf16x8*)&Xb[i + 8] = cvt_f4x2(s[2], s[3]);
    return;
  }
  const int cb = bid - 2048;
  const int n0 = (cb % 48) * 64, k0 = (cb / 48) * 64;
  const int kr = tid >> 4;
  const int c4 = (tid & 15) * 4;
#pragma unroll
  for (int i = 0; i < 4; ++i) {
    const int k = kr + i * 16;
    const float4 w4 = *(const float4*)&W1[(size_t)(k0 + k) * 3072 + n0 + c4];
    sT[c4 + 0][k] = (bf16)w4.x;
    sT[c4 + 1][k] = (bf16)w4.y;
    sT[c4 + 2][k] = (bf16)w4.z;
    sT[c4 + 3][k] = (bf16)w4.w;
  }
  __syncthreads();
  const int r = tid >> 2;
  const int c8 = (tid & 3) * 16;
  *(bf16x8*)&Wt1[(size_t)(n0 + r) * 1024 + k0 + c8] = *(const bf16x8*)&sT[r][c8];
  *(bf16x8*)&Wt1[(size_t)(n0 + r) * 1024 + k0 + c8 + 8] =
      *(const bf16x8*)&sT[r][c8 + 8];
}

// conv_w: W [1024][Nw] f32 -> Wt [Nw][1024] bf16 (standalone, for w_out)
__global__ __launch_bounds__(256) void conv_w_kernel(
    const float* __restrict__ W, bf16* __restrict__ Wt, int Nw) {
  __shared__ bf16 sT[64][72];
  const int tid = threadIdx.x;
  const int n0 = blockIdx.x * 64, k0 = blockIdx.y * 64;
  const int kr = tid >> 4;
  const int c4 = (tid & 15) * 4;
#pragma unroll
  for (int i = 0; i < 4; ++i) {
    const int k = kr + i * 16;
    const float4 w4 = *(const float4*)&W[(size_t)(k0 + k) * Nw + n0 + c4];
    sT[c4 + 0][k] = (bf16)w4.x;
    sT[c4 + 1][k] = (bf16)w4.y;
    sT[c4 + 2][k] = (bf16)w4.z;
    sT[c4 + 3][k] = (bf16)w4.w;
  }
  __syncthreads();
  const int r = tid >> 2;
  const int c8 = (tid & 3) * 16;
  *(bf16x8*)&Wt[(size_t)(n0 + r) * 1024 + k0 + c8] = *(const bf16x8*)&sT[r][c8];
  *(bf16x8*)&Wt[(size_t)(n0 + r) * 1024 + k0 + c8 + 8] =
      *(const bf16x8*)&sT[r][c8 + 8];
}

// ---------------------------------------------------------------------------
// QKV scatter epilogue (shared by both GEMM1 variants)
// ---------------------------------------------------------------------------
static __device__ __forceinline__ void qkv_epilogue(
    f32x4 acc[4][4], const float* bias, bf16* Qb, bf16* Kb, bf16* Vt, int m0,
    int n0, int wr, int wc, int lg, int lr) {
  if (n0 < 2048) {
    bf16* dst = (n0 < 1024) ? Qb : Kb;
#pragma unroll
    for (int m = 0; m < 4; ++m) {
#pragma unroll
      for (int n = 0; n < 4; ++n) {
        const int colg = n0 + wc * 64 + n * 16 + lr;
        const int col = colg & 1023;
        const int h = col >> 6, d = col & 63;
        const float bv = bias[colg];
#pragma unroll
        for (int i = 0; i < 4; ++i) {
          const int row = m0 + wr * 64 + m * 16 + lg * 4 + i;
          const int bb = row >> 11, ll = row & 2047;
          dst[((size_t)((bb * 16 + h) * 2048 + ll)) * 64 + d] =
              (bf16)(acc[m][n][i] + bv);
        }
      }
    }
  } else {
#pragma unroll
    for (int m = 0; m < 4; ++m) {
#pragma unroll
      for (int n = 0; n < 4; ++n) {
        const int colg = n0 + wc * 64 + n * 16 + lr;
        const int col = colg & 1023;
        const int h = col >> 6, d = col & 63;
        const float bv = bias[colg];
        const int row0 = m0 + wr * 64 + m * 16 + lg * 4;
        const int bb = row0 >> 11, ll0 = row0 & 2047;
        bf16x4 pk;
#pragma unroll
        for (int i = 0; i < 4; ++i) pk[i] = (bf16)(acc[m][n][i] + bv);
        *(bf16x4*)&Vt[((size_t)((bb * 16 + h) * 64 + d)) * 2048 + ll0] = pk;
      }
    }
  }
}

// ---------------------------------------------------------------------------
// GEMM1 (big-ws): both operands bf16 via global_load_lds, DOUBLE-BUFFERED
// with counted vmcnt(8) (T3 minimum-2-phase). 128x128 tile, BK=64, 4 waves.
// 1-D grid 1536 with XCD swizzle: n-major chunks per XCD (B panel L2-hot).
// ---------------------------------------------------------------------------
__global__ __launch_bounds__(256, 2) void gemm_qkv_bf16_kernel(
    const bf16* __restrict__ Xb, const bf16* __restrict__ Wt,
    const float* __restrict__ bias, bf16* __restrict__ Qb,
    bf16* __restrict__ Kb, bf16* __restrict__ Vt) {
  constexpr int K = 1024, NT = K / 64;
  __shared__ __align__(16) bf16 sA[2][128 * 64];
  __shared__ __align__(16) bf16 sB[2][128 * 64];
  const int tid = threadIdx.x;
  const int id = blockIdx.x;
  const int swz = (id & 7) * 192 + (id >> 3);  // bijective (1536 = 8*192)
  const int m0 = (swz & 63) * 128, n0 = (swz >> 6) * 128;
  const int wid = tid >> 6, lane = tid & 63;
  const int wr = wid >> 1, wc = wid & 1;
  const int lg = lane >> 4, lr = lane & 15;

  const f32x4 fz = {0.f, 0.f, 0.f, 0.f};
  f32x4 acc[4][4];
#pragma unroll
  for (int m = 0; m < 4; ++m)
#pragma unroll
    for (int n = 0; n < 4; ++n) acc[m][n] = fz;

#define GSTAGE(buf, k0_)                                                \
  {                                                                     \
    const int k0s = (k0_);                                              \
    _Pragma("unroll") for (int s = 0; s < 4; ++s) {                     \
      const int o = s * 2048 + tid * 8;                                 \
      const int row = o >> 6, col = o & 63;                             \
      gll16(&Xb[(size_t)(m0 + row) * K + k0s + col], &sA[buf][o]);      \
      gll16(&Wt[(size_t)(n0 + row) * K + k0s + col], &sB[buf][o]);      \
    }                                                                   \
  }

  GSTAGE(0, 0);
  for (int t = 0; t < NT; ++t) {
    const int buf = t & 1;
    __builtin_amdgcn_s_barrier();  // all waves done reading buf^1
    if (t + 1 < NT) {
      GSTAGE(buf ^ 1, (t + 1) * 64);
      asm volatile("s_waitcnt vmcnt(8)" ::: "memory");  // tile t landed
    } else {
      asm volatile("s_waitcnt vmcnt(0)" ::: "memory");
    }
    __builtin_amdgcn_s_barrier();  // tile t visible

#pragma unroll
    for (int ks = 0; ks < 2; ++ks) {
      bf16x8 af[4], bfv[4];
#pragma unroll
      for (int m = 0; m < 4; ++m)
        af[m] = *(const bf16x8*)&sA[buf][(wr * 64 + m * 16 + lr) * 64 + ks * 32 + 8 * lg];
#pragma unroll
      for (int n = 0; n < 4; ++n)
        bfv[n] = *(const bf16x8*)&sB[buf][(wc * 64 + n * 16 + lr) * 64 + ks * 32 + 8 * lg];
#pragma unroll
      for (int m = 0; m < 4; ++m)
#pragma unroll
        for (int n = 0; n < 4; ++n)
          acc[m][n] = MFMA16(af[m], bfv[n], acc[m][n]);
    }
  }
#undef GSTAGE
  qkv_epilogue(acc, bias, Qb, Kb, Vt, m0, n0, wr, wc, lg, lr);
}

// ---------------------------------------------------------------------------
// GEMM1 (fallback, ws < 70MB): A f32 reg-staged, B via gll, single-buffered.
// ---------------------------------------------------------------------------
__global__ __launch_bounds__(256) void gemm_qkv_kernel(
    const float* __restrict__ X, const bf16* __restrict__ Wt,
    const float* __restrict__ bias, bf16* __restrict__ Qb,
    bf16* __restrict__ Kb, bf16* __restrict__ Vt) {
  constexpr int K = 1024;
  __shared__ __align__(16) bf16 sA[128 * 64];
  __shared__ __align__(16) bf16 sB[128 * 64];
  const int tid = threadIdx.x;
  const int m0 = blockIdx.y * 128, n0 = blockIdx.x * 128;
  const int wid = tid >> 6, lane = tid & 63;
  const int wr = wid >> 1, wc = wid & 1;
  const int lg = lane >> 4, lr = lane & 15;

  const f32x4 fz = {0.f, 0.f, 0.f, 0.f};
  f32x4 acc[4][4];
#pragma unroll
  for (int m = 0; m < 4; ++m)
#pragma unroll
    for (int n = 0; n < 4; ++n) acc[m][n] = fz;

  for (int k0 = 0; k0 < K; k0 += 64) {
#pragma unroll
    for (int s = 0; s < 4; ++s) {
      const int off = s * 2048 + tid * 8;
      const int row = off >> 6, col = off & 63;
      gll16(&Wt[(size_t)(n0 + row) * K + k0 + col], &sB[off]);
    }
#pragma unroll
    for (int p = 0; p < 4; ++p) {
      const int g = tid + p * 256;
      const int row = g >> 3, c8 = (g & 7) * 8;
      const float4* src = (const float4*)&X[(size_t)(m0 + row) * K + k0 + c8];
      const float4 u = src[0], w = src[1];
      *(bf16x8*)&sA[row * 64 + c8] = cvt_f4x2(u, w);
    }
    __syncthreads();

#pragma unroll
    for (int ks = 0; ks < 2; ++ks) {
      bf16x8 af[4], bfv[4];
#pragma unroll
      for (int m = 0; m < 4; ++m)
        af[m] = *(const bf16x8*)&sA[(wr * 64 + m * 16 + lr) * 64 + ks * 32 + 8 * lg];
#pragma unroll
      for (int n = 0; n < 4; ++n)
        bfv[n] = *(const bf16x8*)&sB[(wc * 64 + n * 16 + lr) * 64 + ks * 32 + 8 * lg];
#pragma unroll
      for (int m = 0; m < 4; ++m)
#pragma unroll
        for (int n = 0; n < 4; ++n)
          acc[m][n] = MFMA16(af[m], bfv[n], acc[m][n]);
    }
    __syncthreads();
  }
  qkv_epilogue(acc, bias, Qb, Kb, Vt, m0, n0, wr, wc, lg, lr);
}

// ---------------------------------------------------------------------------
// Causal flash attention. QBLK=128, KVBLK=64, K/V LDS-staged double-buffered
// (counted vmcnt(4)), T2 XOR-swizzle via pre-swizzled source. Swapped QK^T,
// per-lane softmax in exp2 domain (log2e folded into Q), defer-max THR=11.54.
// ---------------------------------------------------------------------------
#define ATTN_FULL 0
#define ATTN_MASK 1
#define ATTN_SKIP 2

__global__ __launch_bounds__(256, 3) void attn_kernel(
    const bf16* __restrict__ Qb, const bf16* __restrict__ Kb,
    const bf16* __restrict__ Vt, bf16* __restrict__ O) {
  __shared__ __align__(16) bf16 sK[2][64 * 64];
  __shared__ __align__(16) bf16 sV[2][64 * 64];
  __shared__ __align__(16) bf16 sP[4][16 * 72];
  const int tid = threadIdx.x;
  const int qb = 15 - (int)(blockIdx.x >> 6);
  const int bh = blockIdx.x & 63;
  const int q0 = qb * 128;
  const int nt = 2 * qb + 2;
  const int wid = tid >> 6, lane = tid & 63;
  const int lg = lane >> 4, lr = lane & 15;
  const bf16* Kbh = Kb + (size_t)bh * (2048 * 64);
  const bf16* Vth = Vt + (size_t)bh * (64 * 2048);
  bf16* sPw = &sP[wid][0];
  const int swz = (lr & 7) << 3;

  // Q fragments, pre-scaled by (1/8)*log2(e) -> softmax in exp2 domain
  const float qsc = 0.125f * 1.44269504089f;
  const int qrow0 = q0 + wid * 16 + lr;
  const int qrow1 = qrow0 + 64;
  bf16x8 qf[2][2];
#pragma unroll
  for (int h = 0; h < 2; ++h) {
    const bf16* qp =
        Qb + (size_t)bh * (2048 * 64) + (size_t)(qrow0 + 64 * h) * 64 + 8 * lg;
    qf[h][0] = *(const bf16x8*)qp;
    qf[h][1] = *(const bf16x8*)(qp + 32);
#pragma unroll
    for (int j = 0; j < 8; ++j) {
      qf[h][0][j] = (bf16)((float)qf[h][0][j] * qsc);
      qf[h][1][j] = (bf16)((float)qf[h][1][j] * qsc);
    }
  }

  const int pe = tid * 8;
  const int srow0 = pe >> 6;
  const int scol0 = (pe & 63) ^ ((srow0 & 7) << 3);
  const int srow1 = srow0 + 32;
  const int scol1 = (pe & 63) ^ ((srow1 & 7) << 3);

  const f32x4 fz = {0.f, 0.f, 0.f, 0.f};
  f32x4 o[2][4];
#pragma unroll
  for (int h = 0; h < 2; ++h)
#pragma unroll
    for (int n = 0; n < 4; ++n) o[h][n] = fz;
  float m_[2] = {-1e30f, -1e30f}, ssum[2] = {0.f, 0.f};

#define STAGE(buf, kv0_)                                                      \
  {                                                                           \
    const int kv0s = (kv0_);                                                  \
    gll16(&Kbh[(size_t)(kv0s + srow0) * 64 + scol0], &sK[buf][pe]);           \
    gll16(&Kbh[(size_t)(kv0s + srow1) * 64 + scol1], &sK[buf][2048 + pe]);    \
    gll16(&Vth[(size_t)srow0 * 2048 + kv0s + scol0], &sV[buf][pe]);           \
    gll16(&Vth[(size_t)srow1 * 2048 + kv0s + scol1], &sV[buf][2048 + pe]);    \
  }

  STAGE(0, 0);

  for (int t = 0; t < nt; ++t) {
    const int buf = t & 1;
    const int kv0 = t * 64;
    const int mode0 = (t < nt - 2) ? ATTN_FULL : (t == nt - 2 ? ATTN_MASK : ATTN_SKIP);
    const int mode1 = (t < nt - 1) ? ATTN_FULL : ATTN_MASK;

    __builtin_amdgcn_s_barrier();
    if (t + 1 < nt) {
      STAGE(buf ^ 1, kv0 + 64);
      asm volatile("s_waitcnt vmcnt(4)" ::: "memory");
    } else {
      asm volatile("s_waitcnt vmcnt(0)" ::: "memory");
    }
    __builtin_amdgcn_s_barrier();

    const bf16* sKb = sK[buf];
    const bf16* sVb = sV[buf];

    f32x4 s0[4], s1[4];
    __builtin_amdgcn_s_setprio(1);
#pragma unroll
    for (int sub = 0; sub < 4; ++sub) {
      const int e = ((sub * 16 + lr) * 64 + 8 * lg) ^ swz;
      const bf16x8 kf0 = *(const bf16x8*)&sKb[e];
      const bf16x8 kf1 = *(const bf16x8*)&sKb[e ^ 32];
      if (mode0 != ATTN_SKIP) {
        f32x4 sc = MFMA16(kf0, qf[0][0], fz);
        s0[sub] = MFMA16(kf1, qf[0][1], sc);
      }
      f32x4 sc = MFMA16(kf0, qf[1][0], fz);
      s1[sub] = MFMA16(kf1, qf[1][1], sc);
    }
    __builtin_amdgcn_s_setprio(0);

    bf16x8 vf[4][2];
#pragma unroll
    for (int n = 0; n < 4; ++n)
#pragma unroll
      for (int c2 = 0; c2 < 2; ++c2)
        vf[n][c2] = *(const bf16x8*)&sVb[(((n * 16 + lr) * 64 + c2 * 32 + 8 * lg)) ^ swz];

#pragma unroll
    for (int h = 0; h < 2; ++h) {
      const int mode = h ? mode1 : mode0;
      if (mode == ATTN_SKIP) continue;
      const int qrow = h ? qrow1 : qrow0;
      f32x4* sh = h ? s1 : s0;

      float sv[16];
      float rm = -3e30f;
#pragma unroll
      for (int sub = 0; sub < 4; ++sub)
#pragma unroll
        for (int i = 0; i < 4; ++i) {
          float v = sh[sub][i];
          if (mode == ATTN_MASK) {
            const int kvg = kv0 + sub * 16 + lg * 4 + i;
            v = (kvg > qrow) ? -3e30f : v;
          }
          sv[sub * 4 + i] = v;
          rm = fmaxf(rm, v);
        }
      rm = fmaxf(rm, __shfl_xor(rm, 16));
      rm = fmaxf(rm, __shfl_xor(rm, 32));
      if (!__all(rm <= m_[h] + 11.54f)) {  // T13 defer-max (log2 units)
        const float mn = fmaxf(m_[h], rm);
        const float corr = EXP2(m_[h] - mn);
        ssum[h] *= corr;
        m_[h] = mn;
        float cr[4];
#pragma unroll
        for (int i = 0; i < 4; ++i) cr[i] = __shfl(corr, 4 * lg + i);
#pragma unroll
        for (int n = 0; n < 4; ++n)
#pragma unroll
          for (int i = 0; i < 4; ++i) o[h][n][i] *= cr[i];
      }
      float rs = 0.f;
#pragma unroll
      for (int sub = 0; sub < 4; ++sub) {
        bf16x4 pk;
#pragma unroll
        for (int i = 0; i < 4; ++i) {
          const float p = EXP2(sv[sub * 4 + i] - m_[h]);
          rs += p;
          pk[i] = (bf16)p;
        }
        *(bf16x4*)&sPw[lr * 72 + 16 * sub + 4 * lg] = pk;
      }
      rs += __shfl_xor(rs, 16);
      rs += __shfl_xor(rs, 32);
      ssum[h] += rs;
      __builtin_amdgcn_s_setprio(1);
#pragma unroll
      for (int c2 = 0; c2 < 2; ++c2) {
        const bf16x8 pf = *(const bf16x8*)&sPw[lr * 72 + 32 * c2 + 8 * lg];
#pragma unroll
        for (int n = 0; n < 4; ++n) o[h][n] = MFMA16(pf, vf[n][c2], o[h][n]);
      }
      __builtin_amdgcn_s_setprio(0);
    }
  }
#undef STAGE

  const int b = bh >> 4, hh = bh & 15;
#pragma unroll
  for (int h = 0; h < 2; ++h) {
    const float rinv = 1.f / ssum[h];
    float rv[4];
#pragma unroll
    for (int i = 0; i < 4; ++i) rv[i] = __shfl(rinv, 4 * lg + i);
#pragma unroll
    for (int n = 0; n < 4; ++n)
#pragma unroll
      for (int i = 0; i < 4; ++i) {
        const int q = q0 + 64 * h + wid * 16 + 4 * lg + i;
        O[((size_t)(b * 2048 + q)) * 1024 + hh * 64 + n * 16 + lr] =
            (bf16)(o[h][n][i] * rv[i]);
      }
  }
}

// ---------------------------------------------------------------------------
// GEMM2: out = Ab @ w_out + b. Both sides bf16 gll, double-buffered,
// counted vmcnt(8). 1-D grid 512 with XCD swizzle (1 W-panel per XCD).
// ---------------------------------------------------------------------------
__global__ __launch_bounds__(256, 2) void gemm_out_kernel(
    const bf16* __restrict__ A, const bf16* __restrict__ Wt,
    const float* __restrict__ bias, float* __restrict__ Out) {
  constexpr int K = 1024, N = 1024, NT = K / 64;
  __shared__ __align__(16) bf16 sA[2][128 * 64];
  __shared__ __align__(16) bf16 sB[2][128 * 64];
  const int tid = threadIdx.x;
  const int id = blockIdx.x;
  const int swz = (id & 7) * 64 + (id >> 3);  // bijective (512 = 8*64)
  const int m0 = (swz & 63) * 128, n0 = (swz >> 6) * 128;
  const int wid = tid >> 6, lane = tid & 63;
  const int wr = wid >> 1, wc = wid & 1;
  const int lg = lane >> 4, lr = lane & 15;

  const f32x4 fz = {0.f, 0.f, 0.f, 0.f};
  f32x4 acc[4][4];
#pragma unroll
  for (int m = 0; m < 4; ++m)
#pragma unroll
    for (int n = 0; n < 4; ++n) acc[m][n] = fz;

#define GSTAGE(buf, k0_)                                               \
  {                                                                    \
    const int k0s = (k0_);                                             \
    _Pragma("unroll") for (int s = 0; s < 4; ++s) {                    \
      const int o = s * 2048 + tid * 8;                                \
      const int row = o >> 6, col = o & 63;                            \
      gll16(&A[(size_t)(m0 + row) * K + k0s + col], &sA[buf][o]);      \
      gll16(&Wt[(size_t)(n0 + row) * K + k0s + col], &sB[buf][o]);     \
    }                                                                  \
  }

  GSTAGE(0, 0);
  for (int t = 0; t < NT; ++t) {
    const int buf = t & 1;
    __builtin_amdgcn_s_barrier();
    if (t + 1 < NT) {
      GSTAGE(buf ^ 1, (t + 1) * 64);
      asm volatile("s_waitcnt vmcnt(8)" ::: "memory");
    } else {
      asm volatile("s_waitcnt vmcnt(0)" ::: "memory");
    }
    __builtin_amdgcn_s_barrier();

#pragma unroll
    for (int ks = 0; ks < 2; ++ks) {
      bf16x8 af[4], bfv[4];
#pragma unroll
      for (int m = 0; m < 4; ++m)
        af[m] = *(const bf16x8*)&sA[buf][(wr * 64 + m * 16 + lr) * 64 + ks * 32 + 8 * lg];
#pragma unroll
      for (int n = 0; n < 4; ++n)
        bfv[n] = *(const bf16x8*)&sB[buf][(wc * 64 + n * 16 + lr) * 64 + ks * 32 + 8 * lg];
#pragma unroll
      for (int m = 0; m < 4; ++m)
#pragma unroll
        for (int n = 0; n < 4; ++n)
          acc[m][n] = MFMA16(af[m], bfv[n], acc[m][n]);
    }
  }
#undef GSTAGE

#pragma unroll
  for (int m = 0; m < 4; ++m) {
#pragma unroll
    for (int n = 0; n < 4; ++n) {
      const int colg = n0 + wc * 64 + n * 16 + lr;
      const float bv = bias[colg];
#pragma unroll
      for (int i = 0; i < 4; ++i) {
        const int row = m0 + wr * 64 + m * 16 + lg * 4 + i;
        Out[(size_t)row * N + colg] = acc[m][n][i] + bv;
      }
    }
  }
}

extern "C" void kernel_launch(void* const* d_in, const int* in_sizes, int n_in,
                              void* d_out, int out_size, void* d_ws,
                              size_t ws_size, hipStream_t stream) {
  const float* x     = (const float*)d_in[0];
  const float* w_qkv = (const float*)d_in[1];
  const float* b_qkv = (const float*)d_in[2];
  const float* w_out = (const float*)d_in[3];
  const float* b_out = (const float*)d_in[4];
  float* out = (float*)d_out;

  char* ws = (char*)d_ws;
  const size_t MB = 1024 * 1024;

  if (ws_size >= 70 * MB) {
    // [0,16) Xb -> Ab ; [16,22) Wt1 -> Wt2 at [16,18) ; [22,38) Qb ;
    // [38,54) Kb ; [54,70) Vt
    bf16* Xb  = (bf16*)(ws);
    bf16* Wt1 = (bf16*)(ws + 16 * MB);
    bf16* Qb  = (bf16*)(ws + 22 * MB);
    bf16* Kb  = (bf16*)(ws + 38 * MB);
    bf16* Vt  = (bf16*)(ws + 54 * MB);
    bf16* Ab  = (bf16*)(ws);
    bf16* Wt2 = (bf16*)(ws + 16 * MB);

    conv_all_kernel<<<dim3(2816), 256, 0, stream>>>(x, Xb, w_qkv, Wt1);
    gemm_qkv_bf16_kernel<<<dim3(1536), 256, 0, stream>>>(Xb, Wt1, b_qkv, Qb, Kb, Vt);
    conv_w_kernel<<<dim3(16, 16), 256, 0, stream>>>(w_out, Wt2, 1024);  // Wt1 dead
    attn_kernel<<<dim3(1024), 256, 0, stream>>>(Qb, Kb, Vt, Ab);        // Xb dead
    gemm_out_kernel<<<dim3(512), 256, 0, stream>>>(Ab, Wt2, b_out, out);
  } else {
    // Fallback 64 MB layout
    bf16* Qb  = (bf16*)(ws);
    bf16* Kb  = (bf16*)(ws + 16 * MB);
    bf16* Vt  = (bf16*)(ws + 32 * MB);
    bf16* Wt1 = (bf16*)(ws + 48 * MB);
    bf16* Ab  = (bf16*)(ws + 48 * MB);
    bf16* Wt2 = (bf16*)(ws);

    conv_w_kernel<<<dim3(48, 16), 256, 0, stream>>>(w_qkv, Wt1, 3072);
    gemm_qkv_kernel<<<dim3(24, 64), 256, 0, stream>>>(x, Wt1, b_qkv, Qb, Kb, Vt);
    attn_kernel<<<dim3(1024), 256, 0, stream>>>(Qb, Kb, Vt, Ab);
    conv_w_kernel<<<dim3(16, 16), 256, 0, stream>>>(w_out, Wt2, 1024);
    gemm_out_kernel<<<dim3(512), 256, 0, stream>>>(Ab, Wt2, b_out, out);
  }
}